// Round 11
// baseline (1848.131 us; speedup 1.0000x reference)
//
#include <hip/hip_runtime.h>
#include <hip/hip_bf16.h>
#include <cstdint>
#include <cstddef>

#define T_TOK 4096
#define HID   1024
#define FFN   3584
#define FFI   (2 * FFN)     // interleaved g/u columns: 7168
#define NEXP  8
#define RTOT  (T_TOK * 2)   // total (token, slot) rows = T * top_k
#define MAXT  72            // max 128-row M-tiles: floor(8192/128)+7=71, +1 slack
#define BM 128
#define BN 128
#define BK 64
#define NT1 (FFI / BN)      // 56 N-tiles for gemm1 (interleaved)
#define NT2 (HID / BN)      // 8 N-tiles for gemm2
#define SPLITK2 2           // gemm2 split-K (3584 -> 2 x 1792); partials stored, no atomics
#define KCH2 (FFN / SPLITK2)

typedef __attribute__((ext_vector_type(8))) short bvec8;   // 8 x bf16 (4 VGPR) MFMA operand
typedef __attribute__((ext_vector_type(4))) short bvec4;
typedef __attribute__((ext_vector_type(4))) float fvec4;   // MFMA accumulator
typedef unsigned short u16;

__device__ __forceinline__ u16 f2b(float f) {
  __bf16 b = (__bf16)f;                 // RNE convert
  return __builtin_bit_cast(u16, b);
}
__device__ __forceinline__ float b2f(u16 u) {
  unsigned v = (unsigned)u << 16;       // bf16 -> f32 exact
  return __builtin_bit_cast(float, v);
}

// async global->LDS, 16B per lane. LDS dest must be wave-uniform base (HW adds lane*16).
__device__ __forceinline__ void gload16(const u16* g, u16* l) {
  __builtin_amdgcn_global_load_lds((const __attribute__((address_space(1))) void*)g,
                                   (__attribute__((address_space(3))) void*)l, 16, 0, 0);
}

// bijective XCD swizzle (m204): contiguous chunk of work per XCD
__device__ __forceinline__ int xcd_swz(int bid, int nwg) {
  int q = nwg >> 3, r = nwg & 7;
  int xcd = bid & 7, sub = bid >> 3;
  return (xcd < r ? xcd * (q + 1) : r * (q + 1) + (xcd - r) * q) + sub;
}

// ---------------- router: logits (fp32), top-2, combine weights, counts, + x->bf16 ------
__global__ void router_kernel(const float* __restrict__ x, const float* __restrict__ gw,
                              float* __restrict__ logits, int* __restrict__ tk_id,
                              float* __restrict__ tk_w, int* __restrict__ counts,
                              u16* __restrict__ xb, int full) {
  const int lane = threadIdx.x & 63;
  const int wid  = threadIdx.x >> 6;
  const int t = blockIdx.x * 4 + wid;          // one token per wave
  const float4* xr = (const float4*)(x + (size_t)t * HID);
  float acc[NEXP] = {0.f, 0.f, 0.f, 0.f, 0.f, 0.f, 0.f, 0.f};
#pragma unroll
  for (int it = 0; it < 4; ++it) {
    int k4 = it * 64 + lane;                   // float4 index, covers H/4 = 256
    float4 xv = xr[k4];
    if (xb) {                                  // fused bf16 cast of x
      bvec4 o;
      o[0] = (short)f2b(xv.x); o[1] = (short)f2b(xv.y);
      o[2] = (short)f2b(xv.z); o[3] = (short)f2b(xv.w);
      *(bvec4*)(xb + (size_t)t * HID + k4 * 4) = o;
    }
    const float* gp = gw + (size_t)k4 * 4 * NEXP;
    float xs[4] = {xv.x, xv.y, xv.z, xv.w};
#pragma unroll
    for (int kk = 0; kk < 4; ++kk) {
      float4 ga = ((const float4*)(gp + kk * NEXP))[0];
      float4 gb = ((const float4*)(gp + kk * NEXP))[1];
      acc[0] += xs[kk] * ga.x; acc[1] += xs[kk] * ga.y;
      acc[2] += xs[kk] * ga.z; acc[3] += xs[kk] * ga.w;
      acc[4] += xs[kk] * gb.x; acc[5] += xs[kk] * gb.y;
      acc[6] += xs[kk] * gb.z; acc[7] += xs[kk] * gb.w;
    }
  }
#pragma unroll
  for (int off = 32; off > 0; off >>= 1) {
#pragma unroll
    for (int e = 0; e < NEXP; ++e) acc[e] += __shfl_xor(acc[e], off, 64);
  }
  if (lane < NEXP) logits[(size_t)t * NEXP + lane] = acc[lane];
  if (full && lane == 0) {
    int e0 = 0; float l0 = acc[0];
#pragma unroll
    for (int e = 1; e < NEXP; ++e) if (acc[e] > l0) { l0 = acc[e]; e0 = e; }
    int e1 = -1; float l1 = -3.4e38f;
#pragma unroll
    for (int e = 0; e < NEXP; ++e) if (e != e0 && acc[e] > l1) { l1 = acc[e]; e1 = e; }
    float w0 = 1.f / (1.f + expf(l1 - l0));
    float w1 = 1.f - w0;
    tk_id[t * 2 + 0] = e0; tk_id[t * 2 + 1] = e1;
    tk_w[t * 2 + 0] = w0;  tk_w[t * 2 + 1] = w1;
    atomicAdd(&counts[e0], 1); atomicAdd(&counts[e1], 1);
  }
}

// ---------------- scan: offsets, tile map (single thread; 8 experts, trivial) -----------
__global__ void scan_kernel(const int* __restrict__ counts, int* __restrict__ offsets,
                            int* __restrict__ cursors, int4* __restrict__ tilemap) {
  if (threadIdx.x != 0) return;
  int off = 0, nt = 0;
  for (int e = 0; e < NEXP; ++e) {
    offsets[e] = off; cursors[e] = 0;
    int c = counts[e];
    for (int tm = 0; tm * BM < c; ++tm)
      tilemap[nt++] = make_int4(e, off + tm * BM, min(BM, c - tm * BM), 0);
    off += c;
  }
  offsets[NEXP] = off;
  for (; nt < MAXT; ++nt) tilemap[nt] = make_int4(-1, 0, 0, 0);
}

// ---------------- scatter: row lists + inverse map token->rows --------------------------
__global__ void scatter_kernel(const int* __restrict__ tk_id, const float* __restrict__ tk_w,
                               const int* __restrict__ offsets, int* __restrict__ cursors,
                               int* __restrict__ rowmap, float* __restrict__ roww,
                               int* __restrict__ tokrow) {
  int i = blockIdx.x * 256 + threadIdx.x;      // 0 .. RTOT-1
  int t = i >> 1;
  int e = tk_id[i]; float w = tk_w[i];
  int p = atomicAdd(&cursors[e], 1);
  int r = offsets[e] + p;
  rowmap[r] = t; roww[r] = w;
  tokrow[i] = r;                               // slot i of token t lives at row r
}

// ---------------- transpose-cast (conflict-light): fp32 [R][C] 64x64 tile -> bf16 ------
__global__ void transpose_cast_dual_kernel(const float* __restrict__ w1,
                                           const float* __restrict__ w3,
                                           u16* __restrict__ bi) {
  __shared__ __attribute__((aligned(16))) u16 tile[64 * 72];
  const int z = blockIdx.z, e = z >> 1, half = z & 1;
  const float* src = (half ? w3 : w1) + (size_t)e * HID * FFN;   // [HID][FFN]
  u16* dst = bi + (size_t)e * FFI * HID;
  const int c0 = blockIdx.x * 64, r0 = blockIdx.y * 64;
  const int t = threadIdx.x;
  const int m = t & 15;             // col-group (cols 4m..4m+3)
  const int g = t >> 4;             // row-group (rows 4g..4g+3)
  u16 v[4][4];                      // v[i][j] = elem(row 4g+i, col 4m+j)
#pragma unroll
  for (int i = 0; i < 4; ++i) {
    float4 q = *(const float4*)(src + (size_t)(r0 + 4 * g + i) * FFN + c0 + 4 * m);
    v[i][0] = f2b(q.x); v[i][1] = f2b(q.y); v[i][2] = f2b(q.z); v[i][3] = f2b(q.w);
  }
  const int phys = (g ^ ((m & 3) << 2)) * 4;   // swizzled chunk offset (u16)
#pragma unroll
  for (int j = 0; j < 4; ++j) {
    int c = 4 * m + j;
    bvec4 o; o[0] = (short)v[0][j]; o[1] = (short)v[1][j];
    o[2] = (short)v[2][j]; o[3] = (short)v[3][j];
    *(bvec4*)&tile[c * 72 + phys] = o;
  }
  __syncthreads();
  const int cl = t >> 2;            // output row (source col) 0..63
  const int q  = t & 3;             // 16-elem r-group
  const int base = ((q ^ ((cl >> 2) & 3)) << 4);    // swizzled 16-u16 group offset
  bvec8 ra = *(const bvec8*)&tile[cl * 72 + base];
  bvec8 rb = *(const bvec8*)&tile[cl * 72 + base + 8];
  const int orow = (c0 << 1) + ((cl >> 4) << 5) + (cl & 15) + (half << 4);
  u16* dp = dst + (size_t)orow * HID + r0 + 16 * q;
  *(bvec8*)(dp + 0) = ra;
  *(bvec8*)(dp + 8) = rb;
}

// ---------------- transpose-cast w2 [E][FFN][HID] -> w2t [E][HID][FFN] (same scheme) ----
__global__ void transpose_cast_w2_kernel(const float* __restrict__ w2, u16* __restrict__ w2t) {
  __shared__ __attribute__((aligned(16))) u16 tile[64 * 72];
  const int e = blockIdx.z;
  const float* src = w2 + (size_t)e * FFN * HID;   // [FFN][HID]
  u16* dst = w2t + (size_t)e * HID * FFN;          // [HID][FFN]
  const int c0 = blockIdx.x * 64, r0 = blockIdx.y * 64;
  const int t = threadIdx.x;
  const int m = t & 15;
  const int g = t >> 4;
  u16 v[4][4];
#pragma unroll
  for (int i = 0; i < 4; ++i) {
    float4 q = *(const float4*)(src + (size_t)(r0 + 4 * g + i) * HID + c0 + 4 * m);
    v[i][0] = f2b(q.x); v[i][1] = f2b(q.y); v[i][2] = f2b(q.z); v[i][3] = f2b(q.w);
  }
  const int phys = (g ^ ((m & 3) << 2)) * 4;
#pragma unroll
  for (int j = 0; j < 4; ++j) {
    int c = 4 * m + j;
    bvec4 o; o[0] = (short)v[0][j]; o[1] = (short)v[1][j];
    o[2] = (short)v[2][j]; o[3] = (short)v[3][j];
    *(bvec4*)&tile[c * 72 + phys] = o;
  }
  __syncthreads();
  const int cl = t >> 2;
  const int q  = t & 3;
  const int base = ((q ^ ((cl >> 2) & 3)) << 4);
  bvec8 ra = *(const bvec8*)&tile[cl * 72 + base];
  bvec8 rb = *(const bvec8*)&tile[cl * 72 + base + 8];
  u16* dp = dst + (size_t)(c0 + cl) * FFN + r0 + 16 * q;
  *(bvec8*)(dp + 0) = ra;
  *(bvec8*)(dp + 8) = rb;
}

// ---------------- GEMM1: 128x128, BK=64, R6 2-barrier structure; 5 blocks/CU ------------
// 72 VGPR + 32KB LDS allow 5 blocks/CU (LDS 5x32KB = 160KiB exactly, VGPR cap 102).
// 20 waves/CU hide the per-iteration barrier drain via cross-block overlap (m114).
__launch_bounds__(256, 5)
__global__ void gemm1_kernel(const u16* __restrict__ xb, const u16* __restrict__ bi,
                             const int* __restrict__ rowmap,
                             const int4* __restrict__ tilemap, u16* __restrict__ hbuf) {
  const int wg = xcd_swz(blockIdx.x, NT1 * MAXT);
  const int mt = wg % MAXT;          // M fastest within an XCD chunk -> B-panel L2 reuse
  const int nt = wg / MAXT;
  int4 ti = tilemap[mt];
  if (ti.x < 0) return;
  const int e = ti.x, rowbase = ti.y, mvalid = ti.z;
  const int n0 = nt * BN;

  __shared__ __attribute__((aligned(128))) u16 As[BM * BK];   // 16KB
  __shared__ __attribute__((aligned(128))) u16 Bs[BN * BK];   // 16KB

  const int tid = threadIdx.x;
  const int lane = tid & 63;
  const int wv = tid >> 6;

  const int srow = tid >> 3;                         // 0..31
  const int csrc = ((tid & 7) ^ (srow & 7)) * 8;     // pre-swizzled source chunk (elems)
  const u16* wb = bi + (size_t)e * FFI * HID;
  const u16* gA[4]; const u16* gB[4];
  u16* lA[4]; u16* lB[4];
#pragma unroll
  for (int r = 0; r < 4; ++r) {
    int row = r * 32 + srow;
    int tok = rowmap[min(rowbase + row, RTOT - 1)];
    gA[r] = xb + (size_t)tok * HID + csrc;
    gB[r] = wb + (size_t)(n0 + row) * HID + csrc;
    lA[r] = &As[(r * 32 + wv * 8) * BK];             // wave-uniform dests
    lB[r] = &Bs[(r * 32 + wv * 8) * BK];
  }

  const int wm = (tid >> 7) & 1, wn = (tid >> 6) & 1;   // 2x2 waves, 64x64 each
  const int l15 = lane & 15;
  const int kg = lane >> 4;                          // 0..3
  const int swz = l15 & 7;
  const int aBase = (wm * 64 + l15) * BK;
  const int bBase = (wn * 64 + l15) * BK;
  const int ch0 = ((0 + kg) ^ swz) * 8;              // ks=0 phys chunk (elems)
  const int ch1 = ((4 + kg) ^ swz) * 8;              // ks=1

  fvec4 acc[4][4] = {};

  for (int kt = 0; kt < HID / BK; ++kt) {            // 16 iters
#pragma unroll
    for (int r = 0; r < 4; ++r) { gload16(gA[r], lA[r]); gA[r] += BK; }
#pragma unroll
    for (int r = 0; r < 4; ++r) { gload16(gB[r], lB[r]); gB[r] += BK; }
    __syncthreads();
    bvec8 a0[4], a1[4];
#pragma unroll
    for (int mi = 0; mi < 4; ++mi) {
      a0[mi] = *(const bvec8*)&As[aBase + mi * 16 * BK + ch0];
      a1[mi] = *(const bvec8*)&As[aBase + mi * 16 * BK + ch1];
    }
#pragma unroll
    for (int ni = 0; ni < 4; ++ni) {
      bvec8 b0 = *(const bvec8*)&Bs[bBase + ni * 16 * BK + ch0];
#pragma unroll
      for (int mi = 0; mi < 4; ++mi)
        acc[mi][ni] = __builtin_amdgcn_mfma_f32_16x16x32_bf16(a0[mi], b0, acc[mi][ni], 0, 0, 0);
      bvec8 b1 = *(const bvec8*)&Bs[bBase + ni * 16 * BK + ch1];
#pragma unroll
      for (int mi = 0; mi < 4; ++mi)
        acc[mi][ni] = __builtin_amdgcn_mfma_f32_16x16x32_bf16(a1[mi], b1, acc[mi][ni], 0, 0, 0);
    }
    __syncthreads();
  }
  // epilogue: pair ni (even=g, odd=u): h = silu(g) * u, bf16
  const int rg4 = (lane >> 4) * 4;
#pragma unroll
  for (int mi = 0; mi < 4; ++mi) {
#pragma unroll
    for (int j = 0; j < 4; ++j) {
      int ml = wm * 64 + mi * 16 + rg4 + j;
      if (ml < mvalid) {
        size_t rowoff = (size_t)(rowbase + ml) * FFN + ((n0 + wn * 64) >> 1);
#pragma unroll
        for (int np = 0; np < 2; ++np) {
          float g = acc[mi][2 * np][j], u = acc[mi][2 * np + 1][j];
          float hv = (g / (1.f + expf(-g))) * u;
          hbuf[rowoff + np * 16 + l15] = f2b(hv);
        }
      }
    }
  }
}

// ---------------- GEMM2: 128x128, BK=64, split-K x2, STORE epilogue; 5 blocks/CU --------
__launch_bounds__(256, 5)
__global__ void gemm2_kernel(const u16* __restrict__ hbuf, const u16* __restrict__ w2t,
                             const float* __restrict__ roww,
                             const int4* __restrict__ tilemap, u16* __restrict__ part) {
  const int wg = xcd_swz(blockIdx.x, NT2 * MAXT * SPLITK2);
  const int mt = wg % MAXT;          // M fastest -> B-panel stays in XCD L2
  const int rest = wg / MAXT;
  const int nt = rest % NT2;
  const int sk = rest / NT2;         // 0..1: K chunk [sk*KCH2, (sk+1)*KCH2)
  int4 ti = tilemap[mt];
  if (ti.x < 0) return;
  const int e = ti.x, rowbase = ti.y, mvalid = ti.z;
  const int n0 = nt * BN;
  const int k0 = sk * KCH2;

  __shared__ __attribute__((aligned(128))) u16 As[BM * BK];   // 16KB
  __shared__ __attribute__((aligned(128))) u16 Bs[BN * BK];   // 16KB

  const int tid = threadIdx.x;
  const int lane = tid & 63;
  const int wv = tid >> 6;

  const int srow = tid >> 3;                         // 0..31
  const int csrc = ((tid & 7) ^ (srow & 7)) * 8;
  const u16* wb2 = w2t + (size_t)e * HID * FFN;
  const u16* gA[4]; const u16* gB[4];
  u16* lA[4]; u16* lB[4];
#pragma unroll
  for (int r = 0; r < 4; ++r) {
    int row = r * 32 + srow;
    gA[r] = hbuf + (size_t)min(rowbase + row, RTOT - 1) * FFN + k0 + csrc;
    gB[r] = wb2 + (size_t)(n0 + row) * FFN + k0 + csrc;
    lA[r] = &As[(r * 32 + wv * 8) * BK];
    lB[r] = &Bs[(r * 32 + wv * 8) * BK];
  }

  const int wm = (tid >> 7) & 1, wn = (tid >> 6) & 1;
  const int l15 = lane & 15;
  const int kg = lane >> 4;
  const int swz = l15 & 7;
  const int aBase = (wm * 64 + l15) * BK;
  const int bBase = (wn * 64 + l15) * BK;
  const int ch0 = ((0 + kg) ^ swz) * 8;
  const int ch1 = ((4 + kg) ^ swz) * 8;

  fvec4 acc[4][4] = {};

  for (int kt = 0; kt < KCH2 / BK; ++kt) {           // 28 iters
#pragma unroll
    for (int r = 0; r < 4; ++r) { gload16(gA[r], lA[r]); gA[r] += BK; }
#pragma unroll
    for (int r = 0; r < 4; ++r) { gload16(gB[r], lB[r]); gB[r] += BK; }
    __syncthreads();
    bvec8 a0[4], a1[4];
#pragma unroll
    for (int mi = 0; mi < 4; ++mi) {
      a0[mi] = *(const bvec8*)&As[aBase + mi * 16 * BK + ch0];
      a1[mi] = *(const bvec8*)&As[aBase + mi * 16 * BK + ch1];
    }
#pragma unroll
    for (int ni = 0; ni < 4; ++ni) {
      bvec8 b0 = *(const bvec8*)&Bs[bBase + ni * 16 * BK + ch0];
#pragma unroll
      for (int mi = 0; mi < 4; ++mi)
        acc[mi][ni] = __builtin_amdgcn_mfma_f32_16x16x32_bf16(a0[mi], b0, acc[mi][ni], 0, 0, 0);
      bvec8 b1 = *(const bvec8*)&Bs[bBase + ni * 16 * BK + ch1];
#pragma unroll
      for (int mi = 0; mi < 4; ++mi)
        acc[mi][ni] = __builtin_amdgcn_mfma_f32_16x16x32_bf16(a1[mi], b1, acc[mi][ni], 0, 0, 0);
    }
    __syncthreads();
  }
  // epilogue: weighted bf16 partial store (plain stores, no atomics)
  u16* pp = part + (size_t)sk * RTOT * HID;
  const int rg4 = (lane >> 4) * 4;
#pragma unroll
  for (int mi = 0; mi < 4; ++mi) {
#pragma unroll
    for (int j = 0; j < 4; ++j) {
      int ml = wm * 64 + mi * 16 + rg4 + j;
      if (ml < mvalid) {
        int r = rowbase + ml;
        float wgt = roww[r];
        u16* op = pp + (size_t)r * HID + n0 + wn * 64;
#pragma unroll
        for (int ni = 0; ni < 4; ++ni)
          op[ni * 16 + l15] = f2b(acc[mi][ni][j] * wgt);
      }
    }
  }
}

// ---------------- combine: out[t] = sum over {2 slots} x {2 K-halves} of partials -------
__global__ void combine_kernel(const u16* __restrict__ part, const int* __restrict__ tokrow,
                               float* __restrict__ out) {
  int idx = blockIdx.x * 256 + threadIdx.x;    // 8-col chunk id
  int t = idx >> 7;                            // 128 chunks per token (1024/8)
  int c = (idx & 127) * 8;
  int r0 = tokrow[2 * t], r1 = tokrow[2 * t + 1];
  const size_t sk1 = (size_t)RTOT * HID;
  bvec8 a = *(const bvec8*)(part + (size_t)r0 * HID + c);
  bvec8 b = *(const bvec8*)(part + sk1 + (size_t)r0 * HID + c);
  bvec8 d = *(const bvec8*)(part + (size_t)r1 * HID + c);
  bvec8 f = *(const bvec8*)(part + sk1 + (size_t)r1 * HID + c);
  float* dst = out + (size_t)t * HID + c;
#pragma unroll
  for (int k = 0; k < 8; ++k)
    dst[k] = (b2f((u16)a[k]) + b2f((u16)b[k])) + (b2f((u16)d[k]) + b2f((u16)f[k]));
}

// ---------------- launcher --------------------------------------------------------------
extern "C" void kernel_launch(void* const* d_in, const int* in_sizes, int n_in,
                              void* d_out, int out_size, void* d_ws, size_t ws_size,
                              hipStream_t stream) {
  (void)in_sizes; (void)n_in; (void)out_size;
  const float* x  = (const float*)d_in[0];
  const float* gw = (const float*)d_in[1];
  const float* w1 = (const float*)d_in[2];
  const float* w2 = (const float*)d_in[3];   // NOTE: dict order is w1, w2, w3
  const float* w3 = (const float*)d_in[4];
  float* out = (float*)d_out;
  float* logits = out + (size_t)T_TOK * HID;

  size_t off = 0;
  auto take = [&](size_t b) { size_t o = off; off += (b + 255) & ~(size_t)255; return o; };
  size_t o_xb   = take((size_t)T_TOK * HID * 2);           // x bf16
  size_t o_wt   = take((size_t)NEXP * FFI * HID * 2);      // Bi; later: w2t (front) + part (back)
  size_t o_hb   = take((size_t)RTOT * FFN * 2);            // h bf16
  size_t o_rmap = take((size_t)RTOT * 4);
  size_t o_rw   = take((size_t)RTOT * 4);
  size_t o_tid  = take((size_t)RTOT * 4);
  size_t o_tw   = take((size_t)RTOT * 4);
  size_t o_trow = take((size_t)RTOT * 4);
  size_t o_cnt  = take(4 * NEXP);
  size_t o_ofs  = take(4 * (NEXP + 1));
  size_t o_cur  = take(4 * NEXP);
  size_t o_tmap = take(MAXT * 16);
  size_t total = off;

  if (ws_size < total) {
    hipMemsetAsync(d_out, 0, (size_t)T_TOK * HID * sizeof(float), stream);
    router_kernel<<<T_TOK / 4, 256, 0, stream>>>(x, gw, logits, nullptr, nullptr, nullptr,
                                                 nullptr, 0);
    return;
  }

  char* w = (char*)d_ws;
  u16* xb   = (u16*)(w + o_xb);
  u16* bi   = (u16*)(w + o_wt);
  u16* w2t  = bi;                                   // front 56MB, reused after gemm1
  u16* part = bi + (size_t)NEXP * HID * FFN;        // back 58.7MB free region: 2x16.7MB
  u16* hb   = (u16*)(w + o_hb);
  int*   rmap = (int*)(w + o_rmap);
  float* rw   = (float*)(w + o_rw);
  int*   tkid = (int*)(w + o_tid);
  float* tkw  = (float*)(w + o_tw);
  int*   trow = (int*)(w + o_trow);
  int*   cnt  = (int*)(w + o_cnt);
  int*   ofs  = (int*)(w + o_ofs);
  int*   cur  = (int*)(w + o_cur);
  int4*  tmap = (int4*)(w + o_tmap);

  hipMemsetAsync(cnt, 0, 4 * NEXP, stream);
  router_kernel<<<T_TOK / 4, 256, 0, stream>>>(x, gw, logits, tkid, tkw, cnt, xb, 1);
  scan_kernel<<<1, 64, 0, stream>>>(cnt, ofs, cur, tmap);
  scatter_kernel<<<RTOT / 256, 256, 0, stream>>>(tkid, tkw, ofs, cur, rmap, rw, trow);
  transpose_cast_dual_kernel<<<dim3(FFN / 64, HID / 64, 2 * NEXP), 256, 0, stream>>>(w1, w3, bi);
  gemm1_kernel<<<NT1 * MAXT, 256, 0, stream>>>(xb, bi, rmap, tmap, hb);
  transpose_cast_w2_kernel<<<dim3(HID / 64, FFN / 64, NEXP), 256, 0, stream>>>(w2, w2t);
  gemm2_kernel<<<NT2 * MAXT * SPLITK2, 256, 0, stream>>>(hb, w2t, rw, tmap, part);
  combine_kernel<<<T_TOK * HID / 8 / 256, 256, 0, stream>>>(part, trow, out);
}

// Round 12
// 488.073 us; speedup vs baseline: 3.7866x; 3.7866x over previous
//
#include <hip/hip_runtime.h>
#include <hip/hip_bf16.h>
#include <cstdint>
#include <cstddef>

#define T_TOK 4096
#define HID   1024
#define FFN   3584
#define FFI   (2 * FFN)     // interleaved g/u columns: 7168
#define NEXP  8
#define RTOT  (T_TOK * 2)   // total (token, slot) rows = T * top_k
#define MAXT  72            // max 128-row M-tiles: floor(8192/128)+7=71, +1 slack
#define BM 128
#define BN 128
#define BK 64
#define NT1 (FFI / BN)      // 56 N-tiles for gemm1 (interleaved)
#define NT2 (HID / BN)      // 8 N-tiles for gemm2
#define SPLITK2 2           // gemm2 split-K (3584 -> 2 x 1792); partials stored, no atomics
#define KCH2 (FFN / SPLITK2)

typedef __attribute__((ext_vector_type(8))) short bvec8;   // 8 x bf16 (4 VGPR) MFMA operand
typedef __attribute__((ext_vector_type(4))) short bvec4;
typedef __attribute__((ext_vector_type(4))) float fvec4;   // MFMA accumulator
typedef unsigned short u16;

__device__ __forceinline__ u16 f2b(float f) {
  __bf16 b = (__bf16)f;                 // RNE convert
  return __builtin_bit_cast(u16, b);
}
__device__ __forceinline__ float b2f(u16 u) {
  unsigned v = (unsigned)u << 16;       // bf16 -> f32 exact
  return __builtin_bit_cast(float, v);
}

// async global->LDS, 16B per lane. LDS dest must be wave-uniform base (HW adds lane*16).
__device__ __forceinline__ void gload16(const u16* g, u16* l) {
  __builtin_amdgcn_global_load_lds((const __attribute__((address_space(1))) void*)g,
                                   (__attribute__((address_space(3))) void*)l, 16, 0, 0);
}

// bijective XCD swizzle (m204): contiguous chunk of work per XCD
__device__ __forceinline__ int xcd_swz(int bid, int nwg) {
  int q = nwg >> 3, r = nwg & 7;
  int xcd = bid & 7, sub = bid >> 3;
  return (xcd < r ? xcd * (q + 1) : r * (q + 1) + (xcd - r) * q) + sub;
}

// ---------------- router: logits (fp32), top-2, combine weights, counts, + x->bf16 ------
__global__ void router_kernel(const float* __restrict__ x, const float* __restrict__ gw,
                              float* __restrict__ logits, int* __restrict__ tk_id,
                              float* __restrict__ tk_w, int* __restrict__ counts,
                              u16* __restrict__ xb, int full) {
  const int lane = threadIdx.x & 63;
  const int wid  = threadIdx.x >> 6;
  const int t = blockIdx.x * 4 + wid;          // one token per wave
  const float4* xr = (const float4*)(x + (size_t)t * HID);
  float acc[NEXP] = {0.f, 0.f, 0.f, 0.f, 0.f, 0.f, 0.f, 0.f};
#pragma unroll
  for (int it = 0; it < 4; ++it) {
    int k4 = it * 64 + lane;                   // float4 index, covers H/4 = 256
    float4 xv = xr[k4];
    if (xb) {                                  // fused bf16 cast of x
      bvec4 o;
      o[0] = (short)f2b(xv.x); o[1] = (short)f2b(xv.y);
      o[2] = (short)f2b(xv.z); o[3] = (short)f2b(xv.w);
      *(bvec4*)(xb + (size_t)t * HID + k4 * 4) = o;
    }
    const float* gp = gw + (size_t)k4 * 4 * NEXP;
    float xs[4] = {xv.x, xv.y, xv.z, xv.w};
#pragma unroll
    for (int kk = 0; kk < 4; ++kk) {
      float4 ga = ((const float4*)(gp + kk * NEXP))[0];
      float4 gb = ((const float4*)(gp + kk * NEXP))[1];
      acc[0] += xs[kk] * ga.x; acc[1] += xs[kk] * ga.y;
      acc[2] += xs[kk] * ga.z; acc[3] += xs[kk] * ga.w;
      acc[4] += xs[kk] * gb.x; acc[5] += xs[kk] * gb.y;
      acc[6] += xs[kk] * gb.z; acc[7] += xs[kk] * gb.w;
    }
  }
#pragma unroll
  for (int off = 32; off > 0; off >>= 1) {
#pragma unroll
    for (int e = 0; e < NEXP; ++e) acc[e] += __shfl_xor(acc[e], off, 64);
  }
  if (lane < NEXP) logits[(size_t)t * NEXP + lane] = acc[lane];
  if (full && lane == 0) {
    int e0 = 0; float l0 = acc[0];
#pragma unroll
    for (int e = 1; e < NEXP; ++e) if (acc[e] > l0) { l0 = acc[e]; e0 = e; }
    int e1 = -1; float l1 = -3.4e38f;
#pragma unroll
    for (int e = 0; e < NEXP; ++e) if (e != e0 && acc[e] > l1) { l1 = acc[e]; e1 = e; }
    float w0 = 1.f / (1.f + expf(l1 - l0));
    float w1 = 1.f - w0;
    tk_id[t * 2 + 0] = e0; tk_id[t * 2 + 1] = e1;
    tk_w[t * 2 + 0] = w0;  tk_w[t * 2 + 1] = w1;
    atomicAdd(&counts[e0], 1); atomicAdd(&counts[e1], 1);
  }
}

// ---------------- scan: offsets, tile map (single thread; 8 experts, trivial) -----------
__global__ void scan_kernel(const int* __restrict__ counts, int* __restrict__ offsets,
                            int* __restrict__ cursors, int4* __restrict__ tilemap) {
  if (threadIdx.x != 0) return;
  int off = 0, nt = 0;
  for (int e = 0; e < NEXP; ++e) {
    offsets[e] = off; cursors[e] = 0;
    int c = counts[e];
    for (int tm = 0; tm * BM < c; ++tm)
      tilemap[nt++] = make_int4(e, off + tm * BM, min(BM, c - tm * BM), 0);
    off += c;
  }
  offsets[NEXP] = off;
  for (; nt < MAXT; ++nt) tilemap[nt] = make_int4(-1, 0, 0, 0);
}

// ---------------- scatter: row lists + inverse map token->rows --------------------------
__global__ void scatter_kernel(const int* __restrict__ tk_id, const float* __restrict__ tk_w,
                               const int* __restrict__ offsets, int* __restrict__ cursors,
                               int* __restrict__ rowmap, float* __restrict__ roww,
                               int* __restrict__ tokrow) {
  int i = blockIdx.x * 256 + threadIdx.x;      // 0 .. RTOT-1
  int t = i >> 1;
  int e = tk_id[i]; float w = tk_w[i];
  int p = atomicAdd(&cursors[e], 1);
  int r = offsets[e] + p;
  rowmap[r] = t; roww[r] = w;
  tokrow[i] = r;                               // slot i of token t lives at row r
}

// ---------------- transpose-cast (conflict-light): fp32 [R][C] 64x64 tile -> bf16 ------
__global__ void transpose_cast_dual_kernel(const float* __restrict__ w1,
                                           const float* __restrict__ w3,
                                           u16* __restrict__ bi) {
  __shared__ __attribute__((aligned(16))) u16 tile[64 * 72];
  const int z = blockIdx.z, e = z >> 1, half = z & 1;
  const float* src = (half ? w3 : w1) + (size_t)e * HID * FFN;   // [HID][FFN]
  u16* dst = bi + (size_t)e * FFI * HID;
  const int c0 = blockIdx.x * 64, r0 = blockIdx.y * 64;
  const int t = threadIdx.x;
  const int m = t & 15;             // col-group (cols 4m..4m+3)
  const int g = t >> 4;             // row-group (rows 4g..4g+3)
  u16 v[4][4];                      // v[i][j] = elem(row 4g+i, col 4m+j)
#pragma unroll
  for (int i = 0; i < 4; ++i) {
    float4 q = *(const float4*)(src + (size_t)(r0 + 4 * g + i) * FFN + c0 + 4 * m);
    v[i][0] = f2b(q.x); v[i][1] = f2b(q.y); v[i][2] = f2b(q.z); v[i][3] = f2b(q.w);
  }
  const int phys = (g ^ ((m & 3) << 2)) * 4;   // swizzled chunk offset (u16)
#pragma unroll
  for (int j = 0; j < 4; ++j) {
    int c = 4 * m + j;
    bvec4 o; o[0] = (short)v[0][j]; o[1] = (short)v[1][j];
    o[2] = (short)v[2][j]; o[3] = (short)v[3][j];
    *(bvec4*)&tile[c * 72 + phys] = o;
  }
  __syncthreads();
  const int cl = t >> 2;            // output row (source col) 0..63
  const int q  = t & 3;             // 16-elem r-group
  const int base = ((q ^ ((cl >> 2) & 3)) << 4);    // swizzled 16-u16 group offset
  bvec8 ra = *(const bvec8*)&tile[cl * 72 + base];
  bvec8 rb = *(const bvec8*)&tile[cl * 72 + base + 8];
  const int orow = (c0 << 1) + ((cl >> 4) << 5) + (cl & 15) + (half << 4);
  u16* dp = dst + (size_t)orow * HID + r0 + 16 * q;
  *(bvec8*)(dp + 0) = ra;
  *(bvec8*)(dp + 8) = rb;
}

// ---------------- transpose-cast w2 [E][FFN][HID] -> w2t [E][HID][FFN] (same scheme) ----
__global__ void transpose_cast_w2_kernel(const float* __restrict__ w2, u16* __restrict__ w2t) {
  __shared__ __attribute__((aligned(16))) u16 tile[64 * 72];
  const int e = blockIdx.z;
  const float* src = w2 + (size_t)e * FFN * HID;   // [FFN][HID]
  u16* dst = w2t + (size_t)e * HID * FFN;          // [HID][FFN]
  const int c0 = blockIdx.x * 64, r0 = blockIdx.y * 64;
  const int t = threadIdx.x;
  const int m = t & 15;
  const int g = t >> 4;
  u16 v[4][4];
#pragma unroll
  for (int i = 0; i < 4; ++i) {
    float4 q = *(const float4*)(src + (size_t)(r0 + 4 * g + i) * HID + c0 + 4 * m);
    v[i][0] = f2b(q.x); v[i][1] = f2b(q.y); v[i][2] = f2b(q.z); v[i][3] = f2b(q.w);
  }
  const int phys = (g ^ ((m & 3) << 2)) * 4;
#pragma unroll
  for (int j = 0; j < 4; ++j) {
    int c = 4 * m + j;
    bvec4 o; o[0] = (short)v[0][j]; o[1] = (short)v[1][j];
    o[2] = (short)v[2][j]; o[3] = (short)v[3][j];
    *(bvec4*)&tile[c * 72 + phys] = o;
  }
  __syncthreads();
  const int cl = t >> 2;
  const int q  = t & 3;
  const int base = ((q ^ ((cl >> 2) & 3)) << 4);
  bvec8 ra = *(const bvec8*)&tile[cl * 72 + base];
  bvec8 rb = *(const bvec8*)&tile[cl * 72 + base + 8];
  u16* dp = dst + (size_t)(c0 + cl) * FFN + r0 + 16 * q;
  *(bvec8*)(dp + 0) = ra;
  *(bvec8*)(dp + 8) = rb;
}

// ---------------- GEMM1: 128x128, BK=64, R6 2-barrier structure; 3 blocks/CU ------------
// NOTE (R11 lesson): unified VGPR+AGPR need ≈136 regs -> 3 waves/EU (cap 170) is the max.
// launch_bounds(256,5) capped at 102 and spilled acc to scratch (982us, 1.6GB writes).
__launch_bounds__(256, 3)
__global__ void gemm1_kernel(const u16* __restrict__ xb, const u16* __restrict__ bi,
                             const int* __restrict__ rowmap,
                             const int4* __restrict__ tilemap, u16* __restrict__ hbuf) {
  const int wg = xcd_swz(blockIdx.x, NT1 * MAXT);
  const int mt = wg % MAXT;          // M fastest within an XCD chunk -> B-panel L2 reuse
  const int nt = wg / MAXT;
  int4 ti = tilemap[mt];
  if (ti.x < 0) return;
  const int e = ti.x, rowbase = ti.y, mvalid = ti.z;
  const int n0 = nt * BN;

  __shared__ __attribute__((aligned(128))) u16 As[BM * BK];   // 16KB
  __shared__ __attribute__((aligned(128))) u16 Bs[BN * BK];   // 16KB

  const int tid = threadIdx.x;
  const int lane = tid & 63;
  const int wv = tid >> 6;

  const int srow = tid >> 3;                         // 0..31
  const int csrc = ((tid & 7) ^ (srow & 7)) * 8;     // pre-swizzled source chunk (elems)
  const u16* wb = bi + (size_t)e * FFI * HID;
  const u16* gA[4]; const u16* gB[4];
  u16* lA[4]; u16* lB[4];
#pragma unroll
  for (int r = 0; r < 4; ++r) {
    int row = r * 32 + srow;
    int tok = rowmap[min(rowbase + row, RTOT - 1)];
    gA[r] = xb + (size_t)tok * HID + csrc;
    gB[r] = wb + (size_t)(n0 + row) * HID + csrc;
    lA[r] = &As[(r * 32 + wv * 8) * BK];             // wave-uniform dests
    lB[r] = &Bs[(r * 32 + wv * 8) * BK];
  }

  const int wm = (tid >> 7) & 1, wn = (tid >> 6) & 1;   // 2x2 waves, 64x64 each
  const int l15 = lane & 15;
  const int kg = lane >> 4;                          // 0..3
  const int swz = l15 & 7;
  const int aBase = (wm * 64 + l15) * BK;
  const int bBase = (wn * 64 + l15) * BK;
  const int ch0 = ((0 + kg) ^ swz) * 8;              // ks=0 phys chunk (elems)
  const int ch1 = ((4 + kg) ^ swz) * 8;              // ks=1

  fvec4 acc[4][4] = {};

  for (int kt = 0; kt < HID / BK; ++kt) {            // 16 iters
#pragma unroll
    for (int r = 0; r < 4; ++r) { gload16(gA[r], lA[r]); gA[r] += BK; }
#pragma unroll
    for (int r = 0; r < 4; ++r) { gload16(gB[r], lB[r]); gB[r] += BK; }
    __syncthreads();
    bvec8 a0[4], a1[4];
#pragma unroll
    for (int mi = 0; mi < 4; ++mi) {
      a0[mi] = *(const bvec8*)&As[aBase + mi * 16 * BK + ch0];
      a1[mi] = *(const bvec8*)&As[aBase + mi * 16 * BK + ch1];
    }
#pragma unroll
    for (int ni = 0; ni < 4; ++ni) {
      bvec8 b0 = *(const bvec8*)&Bs[bBase + ni * 16 * BK + ch0];
#pragma unroll
      for (int mi = 0; mi < 4; ++mi)
        acc[mi][ni] = __builtin_amdgcn_mfma_f32_16x16x32_bf16(a0[mi], b0, acc[mi][ni], 0, 0, 0);
      bvec8 b1 = *(const bvec8*)&Bs[bBase + ni * 16 * BK + ch1];
#pragma unroll
      for (int mi = 0; mi < 4; ++mi)
        acc[mi][ni] = __builtin_amdgcn_mfma_f32_16x16x32_bf16(a1[mi], b1, acc[mi][ni], 0, 0, 0);
    }
    __syncthreads();
  }
  // epilogue: pair ni (even=g, odd=u): h = silu(g) * u, bf16
  const int rg4 = (lane >> 4) * 4;
#pragma unroll
  for (int mi = 0; mi < 4; ++mi) {
#pragma unroll
    for (int j = 0; j < 4; ++j) {
      int ml = wm * 64 + mi * 16 + rg4 + j;
      if (ml < mvalid) {
        size_t rowoff = (size_t)(rowbase + ml) * FFN + ((n0 + wn * 64) >> 1);
#pragma unroll
        for (int np = 0; np < 2; ++np) {
          float g = acc[mi][2 * np][j], u = acc[mi][2 * np + 1][j];
          float hv = (g / (1.f + expf(-g))) * u;
          hbuf[rowoff + np * 16 + l15] = f2b(hv);
        }
      }
    }
  }
}

// ---------------- GEMM2: 128x128, BK=64, split-K x2, STORE epilogue; 3 blocks/CU --------
__launch_bounds__(256, 3)
__global__ void gemm2_kernel(const u16* __restrict__ hbuf, const u16* __restrict__ w2t,
                             const float* __restrict__ roww,
                             const int4* __restrict__ tilemap, u16* __restrict__ part) {
  const int wg = xcd_swz(blockIdx.x, NT2 * MAXT * SPLITK2);
  const int mt = wg % MAXT;          // M fastest -> B-panel stays in XCD L2
  const int rest = wg / MAXT;
  const int nt = rest % NT2;
  const int sk = rest / NT2;         // 0..1: K chunk [sk*KCH2, (sk+1)*KCH2)
  int4 ti = tilemap[mt];
  if (ti.x < 0) return;
  const int e = ti.x, rowbase = ti.y, mvalid = ti.z;
  const int n0 = nt * BN;
  const int k0 = sk * KCH2;

  __shared__ __attribute__((aligned(128))) u16 As[BM * BK];   // 16KB
  __shared__ __attribute__((aligned(128))) u16 Bs[BN * BK];   // 16KB

  const int tid = threadIdx.x;
  const int lane = tid & 63;
  const int wv = tid >> 6;

  const int srow = tid >> 3;                         // 0..31
  const int csrc = ((tid & 7) ^ (srow & 7)) * 8;
  const u16* wb2 = w2t + (size_t)e * HID * FFN;
  const u16* gA[4]; const u16* gB[4];
  u16* lA[4]; u16* lB[4];
#pragma unroll
  for (int r = 0; r < 4; ++r) {
    int row = r * 32 + srow;
    gA[r] = hbuf + (size_t)min(rowbase + row, RTOT - 1) * FFN + k0 + csrc;
    gB[r] = wb2 + (size_t)(n0 + row) * FFN + k0 + csrc;
    lA[r] = &As[(r * 32 + wv * 8) * BK];
    lB[r] = &Bs[(r * 32 + wv * 8) * BK];
  }

  const int wm = (tid >> 7) & 1, wn = (tid >> 6) & 1;
  const int l15 = lane & 15;
  const int kg = lane >> 4;
  const int swz = l15 & 7;
  const int aBase = (wm * 64 + l15) * BK;
  const int bBase = (wn * 64 + l15) * BK;
  const int ch0 = ((0 + kg) ^ swz) * 8;
  const int ch1 = ((4 + kg) ^ swz) * 8;

  fvec4 acc[4][4] = {};

  for (int kt = 0; kt < KCH2 / BK; ++kt) {           // 28 iters
#pragma unroll
    for (int r = 0; r < 4; ++r) { gload16(gA[r], lA[r]); gA[r] += BK; }
#pragma unroll
    for (int r = 0; r < 4; ++r) { gload16(gB[r], lB[r]); gB[r] += BK; }
    __syncthreads();
    bvec8 a0[4], a1[4];
#pragma unroll
    for (int mi = 0; mi < 4; ++mi) {
      a0[mi] = *(const bvec8*)&As[aBase + mi * 16 * BK + ch0];
      a1[mi] = *(const bvec8*)&As[aBase + mi * 16 * BK + ch1];
    }
#pragma unroll
    for (int ni = 0; ni < 4; ++ni) {
      bvec8 b0 = *(const bvec8*)&Bs[bBase + ni * 16 * BK + ch0];
#pragma unroll
      for (int mi = 0; mi < 4; ++mi)
        acc[mi][ni] = __builtin_amdgcn_mfma_f32_16x16x32_bf16(a0[mi], b0, acc[mi][ni], 0, 0, 0);
      bvec8 b1 = *(const bvec8*)&Bs[bBase + ni * 16 * BK + ch1];
#pragma unroll
      for (int mi = 0; mi < 4; ++mi)
        acc[mi][ni] = __builtin_amdgcn_mfma_f32_16x16x32_bf16(a1[mi], b1, acc[mi][ni], 0, 0, 0);
    }
    __syncthreads();
  }
  // epilogue: weighted bf16 partial store (plain stores, no atomics)
  u16* pp = part + (size_t)sk * RTOT * HID;
  const int rg4 = (lane >> 4) * 4;
#pragma unroll
  for (int mi = 0; mi < 4; ++mi) {
#pragma unroll
    for (int j = 0; j < 4; ++j) {
      int ml = wm * 64 + mi * 16 + rg4 + j;
      if (ml < mvalid) {
        int r = rowbase + ml;
        float wgt = roww[r];
        u16* op = pp + (size_t)r * HID + n0 + wn * 64;
#pragma unroll
        for (int ni = 0; ni < 4; ++ni)
          op[ni * 16 + l15] = f2b(acc[mi][ni][j] * wgt);
      }
    }
  }
}

// ---------------- combine: out[t] = sum over {2 slots} x {2 K-halves} of partials -------
__global__ void combine_kernel(const u16* __restrict__ part, const int* __restrict__ tokrow,
                               float* __restrict__ out) {
  int idx = blockIdx.x * 256 + threadIdx.x;    // 8-col chunk id
  int t = idx >> 7;                            // 128 chunks per token (1024/8)
  int c = (idx & 127) * 8;
  int r0 = tokrow[2 * t], r1 = tokrow[2 * t + 1];
  const size_t sk1 = (size_t)RTOT * HID;
  bvec8 a = *(const bvec8*)(part + (size_t)r0 * HID + c);
  bvec8 b = *(const bvec8*)(part + sk1 + (size_t)r0 * HID + c);
  bvec8 d = *(const bvec8*)(part + (size_t)r1 * HID + c);
  bvec8 f = *(const bvec8*)(part + sk1 + (size_t)r1 * HID + c);
  float* dst = out + (size_t)t * HID + c;
#pragma unroll
  for (int k = 0; k < 8; ++k)
    dst[k] = (b2f((u16)a[k]) + b2f((u16)b[k])) + (b2f((u16)d[k]) + b2f((u16)f[k]));
}

// ---------------- launcher --------------------------------------------------------------
extern "C" void kernel_launch(void* const* d_in, const int* in_sizes, int n_in,
                              void* d_out, int out_size, void* d_ws, size_t ws_size,
                              hipStream_t stream) {
  (void)in_sizes; (void)n_in; (void)out_size;
  const float* x  = (const float*)d_in[0];
  const float* gw = (const float*)d_in[1];
  const float* w1 = (const float*)d_in[2];
  const float* w2 = (const float*)d_in[3];   // NOTE: dict order is w1, w2, w3
  const float* w3 = (const float*)d_in[4];
  float* out = (float*)d_out;
  float* logits = out + (size_t)T_TOK * HID;

  size_t off = 0;
  auto take = [&](size_t b) { size_t o = off; off += (b + 255) & ~(size_t)255; return o; };
  size_t o_xb   = take((size_t)T_TOK * HID * 2);           // x bf16
  size_t o_wt   = take((size_t)NEXP * FFI * HID * 2);      // Bi; later: w2t (front) + part (back)
  size_t o_hb   = take((size_t)RTOT * FFN * 2);            // h bf16
  size_t o_rmap = take((size_t)RTOT * 4);
  size_t o_rw   = take((size_t)RTOT * 4);
  size_t o_tid  = take((size_t)RTOT * 4);
  size_t o_tw   = take((size_t)RTOT * 4);
  size_t o_trow = take((size_t)RTOT * 4);
  size_t o_cnt  = take(4 * NEXP);
  size_t o_ofs  = take(4 * (NEXP + 1));
  size_t o_cur  = take(4 * NEXP);
  size_t o_tmap = take(MAXT * 16);
  size_t total = off;

  if (ws_size < total) {
    hipMemsetAsync(d_out, 0, (size_t)T_TOK * HID * sizeof(float), stream);
    router_kernel<<<T_TOK / 4, 256, 0, stream>>>(x, gw, logits, nullptr, nullptr, nullptr,
                                                 nullptr, 0);
    return;
  }

  char* w = (char*)d_ws;
  u16* xb   = (u16*)(w + o_xb);
  u16* bi   = (u16*)(w + o_wt);
  u16* w2t  = bi;                                   // front 56MB, reused after gemm1
  u16* part = bi + (size_t)NEXP * HID * FFN;        // back 58.7MB free region: 2x16.7MB
  u16* hb   = (u16*)(w + o_hb);
  int*   rmap = (int*)(w + o_rmap);
  float* rw   = (float*)(w + o_rw);
  int*   tkid = (int*)(w + o_tid);
  float* tkw  = (float*)(w + o_tw);
  int*   trow = (int*)(w + o_trow);
  int*   cnt  = (int*)(w + o_cnt);
  int*   ofs  = (int*)(w + o_ofs);
  int*   cur  = (int*)(w + o_cur);
  int4*  tmap = (int4*)(w + o_tmap);

  hipMemsetAsync(cnt, 0, 4 * NEXP, stream);
  router_kernel<<<T_TOK / 4, 256, 0, stream>>>(x, gw, logits, tkid, tkw, cnt, xb, 1);
  scan_kernel<<<1, 64, 0, stream>>>(cnt, ofs, cur, tmap);
  scatter_kernel<<<RTOT / 256, 256, 0, stream>>>(tkid, tkw, ofs, cur, rmap, rw, trow);
  transpose_cast_dual_kernel<<<dim3(FFN / 64, HID / 64, 2 * NEXP), 256, 0, stream>>>(w1, w3, bi);
  gemm1_kernel<<<NT1 * MAXT, 256, 0, stream>>>(xb, bi, rmap, tmap, hb);
  transpose_cast_w2_kernel<<<dim3(HID / 64, FFN / 64, NEXP), 256, 0, stream>>>(w2, w2t);
  gemm2_kernel<<<NT2 * MAXT * SPLITK2, 256, 0, stream>>>(hb, w2t, rw, tmap, part);
  combine_kernel<<<T_TOK * HID / 8 / 256, 256, 0, stream>>>(part, trow, out);
}

// Round 13
// 486.546 us; speedup vs baseline: 3.7985x; 1.0031x over previous
//
#include <hip/hip_runtime.h>
#include <hip/hip_bf16.h>
#include <cstdint>
#include <cstddef>

#define T_TOK 4096
#define HID   1024
#define FFN   3584
#define FFI   (2 * FFN)     // interleaved g/u columns: 7168
#define NEXP  8
#define RTOT  (T_TOK * 2)   // total (token, slot) rows = T * top_k
#define MAXT  72            // max 128-row M-tiles: floor(8192/128)+7=71, +1 slack
#define BM 128
#define BN 128
#define BK 64
#define NT1 (FFI / BN)      // 56 N-tiles for gemm1 (interleaved)
#define NT2 (HID / BN)      // 8 N-tiles for gemm2
#define SPLITK2 2           // gemm2 split-K (3584 -> 2 x 1792); partials stored, no atomics
#define KCH2 (FFN / SPLITK2)

typedef __attribute__((ext_vector_type(8))) short bvec8;   // 8 x bf16 (4 VGPR) MFMA operand
typedef __attribute__((ext_vector_type(4))) short bvec4;
typedef __attribute__((ext_vector_type(4))) float fvec4;   // MFMA accumulator
typedef unsigned short u16;

__device__ __forceinline__ u16 f2b(float f) {
  __bf16 b = (__bf16)f;                 // RNE convert
  return __builtin_bit_cast(u16, b);
}
__device__ __forceinline__ float b2f(u16 u) {
  unsigned v = (unsigned)u << 16;       // bf16 -> f32 exact
  return __builtin_bit_cast(float, v);
}

// async global->LDS, 16B per lane. LDS dest must be wave-uniform base (HW adds lane*16).
__device__ __forceinline__ void gload16(const u16* g, u16* l) {
  __builtin_amdgcn_global_load_lds((const __attribute__((address_space(1))) void*)g,
                                   (__attribute__((address_space(3))) void*)l, 16, 0, 0);
}

// bijective XCD swizzle (m204): contiguous chunk of work per XCD
__device__ __forceinline__ int xcd_swz(int bid, int nwg) {
  int q = nwg >> 3, r = nwg & 7;
  int xcd = bid & 7, sub = bid >> 3;
  return (xcd < r ? xcd * (q + 1) : r * (q + 1) + (xcd - r) * q) + sub;
}

// ---------------- router: logits (fp32), top-2, combine weights, counts, + x->bf16 ------
__global__ void router_kernel(const float* __restrict__ x, const float* __restrict__ gw,
                              float* __restrict__ logits, int* __restrict__ tk_id,
                              float* __restrict__ tk_w, int* __restrict__ counts,
                              u16* __restrict__ xb, int full) {
  const int lane = threadIdx.x & 63;
  const int wid  = threadIdx.x >> 6;
  const int t = blockIdx.x * 4 + wid;          // one token per wave
  const float4* xr = (const float4*)(x + (size_t)t * HID);
  float acc[NEXP] = {0.f, 0.f, 0.f, 0.f, 0.f, 0.f, 0.f, 0.f};
#pragma unroll
  for (int it = 0; it < 4; ++it) {
    int k4 = it * 64 + lane;                   // float4 index, covers H/4 = 256
    float4 xv = xr[k4];
    if (xb) {                                  // fused bf16 cast of x
      bvec4 o;
      o[0] = (short)f2b(xv.x); o[1] = (short)f2b(xv.y);
      o[2] = (short)f2b(xv.z); o[3] = (short)f2b(xv.w);
      *(bvec4*)(xb + (size_t)t * HID + k4 * 4) = o;
    }
    const float* gp = gw + (size_t)k4 * 4 * NEXP;
    float xs[4] = {xv.x, xv.y, xv.z, xv.w};
#pragma unroll
    for (int kk = 0; kk < 4; ++kk) {
      float4 ga = ((const float4*)(gp + kk * NEXP))[0];
      float4 gb = ((const float4*)(gp + kk * NEXP))[1];
      acc[0] += xs[kk] * ga.x; acc[1] += xs[kk] * ga.y;
      acc[2] += xs[kk] * ga.z; acc[3] += xs[kk] * ga.w;
      acc[4] += xs[kk] * gb.x; acc[5] += xs[kk] * gb.y;
      acc[6] += xs[kk] * gb.z; acc[7] += xs[kk] * gb.w;
    }
  }
#pragma unroll
  for (int off = 32; off > 0; off >>= 1) {
#pragma unroll
    for (int e = 0; e < NEXP; ++e) acc[e] += __shfl_xor(acc[e], off, 64);
  }
  if (lane < NEXP) logits[(size_t)t * NEXP + lane] = acc[lane];
  if (full && lane == 0) {
    int e0 = 0; float l0 = acc[0];
#pragma unroll
    for (int e = 1; e < NEXP; ++e) if (acc[e] > l0) { l0 = acc[e]; e0 = e; }
    int e1 = -1; float l1 = -3.4e38f;
#pragma unroll
    for (int e = 0; e < NEXP; ++e) if (e != e0 && acc[e] > l1) { l1 = acc[e]; e1 = e; }
    float w0 = 1.f / (1.f + expf(l1 - l0));
    float w1 = 1.f - w0;
    tk_id[t * 2 + 0] = e0; tk_id[t * 2 + 1] = e1;
    tk_w[t * 2 + 0] = w0;  tk_w[t * 2 + 1] = w1;
    atomicAdd(&counts[e0], 1); atomicAdd(&counts[e1], 1);
  }
}

// ---------------- scan: offsets + tile map, PARALLEL (was single-thread serial) ---------
// Thread e<8 computes its own prefix from the 8 counts (L2-hot) and writes its expert's
// tilemap slice as independent stores; padding fill strided over all 64 threads.
__global__ void scan_kernel(const int* __restrict__ counts, int* __restrict__ offsets,
                            int* __restrict__ cursors, int4* __restrict__ tilemap) {
  __shared__ int c[NEXP];
  __shared__ int tbase[NEXP + 1];
  const int t = threadIdx.x;
  if (t < NEXP) c[t] = counts[t];
  __syncthreads();
  if (t < NEXP) {
    int off = 0, tiles = 0;
    for (int e = 0; e < t; ++e) { off += c[e]; tiles += (c[e] + BM - 1) / BM; }
    offsets[t] = off; cursors[t] = 0;
    if (t == NEXP - 1) {
      offsets[NEXP] = off + c[t];
      tbase[NEXP] = tiles + (c[t] + BM - 1) / BM;
    }
    tbase[t] = tiles;
    const int cc = c[t];
    for (int tm = 0; tm * BM < cc; ++tm)
      tilemap[tiles + tm] = make_int4(t, off + tm * BM, min(BM, cc - tm * BM), 0);
  }
  __syncthreads();
  for (int i = tbase[NEXP] + t; i < MAXT; i += 64)
    tilemap[i] = make_int4(-1, 0, 0, 0);
}

// ---------------- scatter: row lists + inverse map token->rows --------------------------
__global__ void scatter_kernel(const int* __restrict__ tk_id, const float* __restrict__ tk_w,
                               const int* __restrict__ offsets, int* __restrict__ cursors,
                               int* __restrict__ rowmap, float* __restrict__ roww,
                               int* __restrict__ tokrow) {
  int i = blockIdx.x * 256 + threadIdx.x;      // 0 .. RTOT-1
  int t = i >> 1;
  int e = tk_id[i]; float w = tk_w[i];
  int p = atomicAdd(&cursors[e], 1);
  int r = offsets[e] + p;
  rowmap[r] = t; roww[r] = w;
  tokrow[i] = r;                               // slot i of token t lives at row r
}

// ---------------- transpose-cast (conflict-light): fp32 [R][C] 64x64 tile -> bf16 ------
__global__ void transpose_cast_dual_kernel(const float* __restrict__ w1,
                                           const float* __restrict__ w3,
                                           u16* __restrict__ bi) {
  __shared__ __attribute__((aligned(16))) u16 tile[64 * 72];
  const int z = blockIdx.z, e = z >> 1, half = z & 1;
  const float* src = (half ? w3 : w1) + (size_t)e * HID * FFN;   // [HID][FFN]
  u16* dst = bi + (size_t)e * FFI * HID;
  const int c0 = blockIdx.x * 64, r0 = blockIdx.y * 64;
  const int t = threadIdx.x;
  const int m = t & 15;             // col-group (cols 4m..4m+3)
  const int g = t >> 4;             // row-group (rows 4g..4g+3)
  u16 v[4][4];                      // v[i][j] = elem(row 4g+i, col 4m+j)
#pragma unroll
  for (int i = 0; i < 4; ++i) {
    float4 q = *(const float4*)(src + (size_t)(r0 + 4 * g + i) * FFN + c0 + 4 * m);
    v[i][0] = f2b(q.x); v[i][1] = f2b(q.y); v[i][2] = f2b(q.z); v[i][3] = f2b(q.w);
  }
  const int phys = (g ^ ((m & 3) << 2)) * 4;   // swizzled chunk offset (u16)
#pragma unroll
  for (int j = 0; j < 4; ++j) {
    int c = 4 * m + j;
    bvec4 o; o[0] = (short)v[0][j]; o[1] = (short)v[1][j];
    o[2] = (short)v[2][j]; o[3] = (short)v[3][j];
    *(bvec4*)&tile[c * 72 + phys] = o;
  }
  __syncthreads();
  const int cl = t >> 2;            // output row (source col) 0..63
  const int q  = t & 3;             // 16-elem r-group
  const int base = ((q ^ ((cl >> 2) & 3)) << 4);    // swizzled 16-u16 group offset
  bvec8 ra = *(const bvec8*)&tile[cl * 72 + base];
  bvec8 rb = *(const bvec8*)&tile[cl * 72 + base + 8];
  const int orow = (c0 << 1) + ((cl >> 4) << 5) + (cl & 15) + (half << 4);
  u16* dp = dst + (size_t)orow * HID + r0 + 16 * q;
  *(bvec8*)(dp + 0) = ra;
  *(bvec8*)(dp + 8) = rb;
}

// ---------------- transpose-cast w2 [E][FFN][HID] -> w2t [E][HID][FFN] (same scheme) ----
__global__ void transpose_cast_w2_kernel(const float* __restrict__ w2, u16* __restrict__ w2t) {
  __shared__ __attribute__((aligned(16))) u16 tile[64 * 72];
  const int e = blockIdx.z;
  const float* src = w2 + (size_t)e * FFN * HID;   // [FFN][HID]
  u16* dst = w2t + (size_t)e * HID * FFN;          // [HID][FFN]
  const int c0 = blockIdx.x * 64, r0 = blockIdx.y * 64;
  const int t = threadIdx.x;
  const int m = t & 15;
  const int g = t >> 4;
  u16 v[4][4];
#pragma unroll
  for (int i = 0; i < 4; ++i) {
    float4 q = *(const float4*)(src + (size_t)(r0 + 4 * g + i) * HID + c0 + 4 * m);
    v[i][0] = f2b(q.x); v[i][1] = f2b(q.y); v[i][2] = f2b(q.z); v[i][3] = f2b(q.w);
  }
  const int phys = (g ^ ((m & 3) << 2)) * 4;
#pragma unroll
  for (int j = 0; j < 4; ++j) {
    int c = 4 * m + j;
    bvec4 o; o[0] = (short)v[0][j]; o[1] = (short)v[1][j];
    o[2] = (short)v[2][j]; o[3] = (short)v[3][j];
    *(bvec4*)&tile[c * 72 + phys] = o;
  }
  __syncthreads();
  const int cl = t >> 2;
  const int q  = t & 3;
  const int base = ((q ^ ((cl >> 2) & 3)) << 4);
  bvec8 ra = *(const bvec8*)&tile[cl * 72 + base];
  bvec8 rb = *(const bvec8*)&tile[cl * 72 + base + 8];
  u16* dp = dst + (size_t)(c0 + cl) * FFN + r0 + 16 * q;
  *(bvec8*)(dp + 0) = ra;
  *(bvec8*)(dp + 8) = rb;
}

// ---------------- GEMM1: 128x128, BK=64, R6 2-barrier structure; 3 blocks/CU ------------
// NOTE (R11 lesson): unified VGPR+AGPR need ≈136 regs -> 3 waves/EU (cap 170) is the max.
// launch_bounds(256,5) capped at 102 and spilled acc to scratch (982us, 1.6GB writes).
__launch_bounds__(256, 3)
__global__ void gemm1_kernel(const u16* __restrict__ xb, const u16* __restrict__ bi,
                             const int* __restrict__ rowmap,
                             const int4* __restrict__ tilemap, u16* __restrict__ hbuf) {
  const int wg = xcd_swz(blockIdx.x, NT1 * MAXT);
  const int mt = wg % MAXT;          // M fastest within an XCD chunk -> B-panel L2 reuse
  const int nt = wg / MAXT;
  int4 ti = tilemap[mt];
  if (ti.x < 0) return;
  const int e = ti.x, rowbase = ti.y, mvalid = ti.z;
  const int n0 = nt * BN;

  __shared__ __attribute__((aligned(128))) u16 As[BM * BK];   // 16KB
  __shared__ __attribute__((aligned(128))) u16 Bs[BN * BK];   // 16KB

  const int tid = threadIdx.x;
  const int lane = tid & 63;
  const int wv = tid >> 6;

  const int srow = tid >> 3;                         // 0..31
  const int csrc = ((tid & 7) ^ (srow & 7)) * 8;     // pre-swizzled source chunk (elems)
  const u16* wb = bi + (size_t)e * FFI * HID;
  const u16* gA[4]; const u16* gB[4];
  u16* lA[4]; u16* lB[4];
#pragma unroll
  for (int r = 0; r < 4; ++r) {
    int row = r * 32 + srow;
    int tok = rowmap[min(rowbase + row, RTOT - 1)];
    gA[r] = xb + (size_t)tok * HID + csrc;
    gB[r] = wb + (size_t)(n0 + row) * HID + csrc;
    lA[r] = &As[(r * 32 + wv * 8) * BK];             // wave-uniform dests
    lB[r] = &Bs[(r * 32 + wv * 8) * BK];
  }

  const int wm = (tid >> 7) & 1, wn = (tid >> 6) & 1;   // 2x2 waves, 64x64 each
  const int l15 = lane & 15;
  const int kg = lane >> 4;                          // 0..3
  const int swz = l15 & 7;
  const int aBase = (wm * 64 + l15) * BK;
  const int bBase = (wn * 64 + l15) * BK;
  const int ch0 = ((0 + kg) ^ swz) * 8;              // ks=0 phys chunk (elems)
  const int ch1 = ((4 + kg) ^ swz) * 8;              // ks=1

  fvec4 acc[4][4] = {};

  for (int kt = 0; kt < HID / BK; ++kt) {            // 16 iters
#pragma unroll
    for (int r = 0; r < 4; ++r) { gload16(gA[r], lA[r]); gA[r] += BK; }
#pragma unroll
    for (int r = 0; r < 4; ++r) { gload16(gB[r], lB[r]); gB[r] += BK; }
    __syncthreads();
    bvec8 a0[4], a1[4];
#pragma unroll
    for (int mi = 0; mi < 4; ++mi) {
      a0[mi] = *(const bvec8*)&As[aBase + mi * 16 * BK + ch0];
      a1[mi] = *(const bvec8*)&As[aBase + mi * 16 * BK + ch1];
    }
#pragma unroll
    for (int ni = 0; ni < 4; ++ni) {
      bvec8 b0 = *(const bvec8*)&Bs[bBase + ni * 16 * BK + ch0];
#pragma unroll
      for (int mi = 0; mi < 4; ++mi)
        acc[mi][ni] = __builtin_amdgcn_mfma_f32_16x16x32_bf16(a0[mi], b0, acc[mi][ni], 0, 0, 0);
      bvec8 b1 = *(const bvec8*)&Bs[bBase + ni * 16 * BK + ch1];
#pragma unroll
      for (int mi = 0; mi < 4; ++mi)
        acc[mi][ni] = __builtin_amdgcn_mfma_f32_16x16x32_bf16(a1[mi], b1, acc[mi][ni], 0, 0, 0);
    }
    __syncthreads();
  }
  // epilogue: pair ni (even=g, odd=u): h = silu(g) * u, bf16
  const int rg4 = (lane >> 4) * 4;
#pragma unroll
  for (int mi = 0; mi < 4; ++mi) {
#pragma unroll
    for (int j = 0; j < 4; ++j) {
      int ml = wm * 64 + mi * 16 + rg4 + j;
      if (ml < mvalid) {
        size_t rowoff = (size_t)(rowbase + ml) * FFN + ((n0 + wn * 64) >> 1);
#pragma unroll
        for (int np = 0; np < 2; ++np) {
          float g = acc[mi][2 * np][j], u = acc[mi][2 * np + 1][j];
          float hv = (g / (1.f + expf(-g))) * u;
          hbuf[rowoff + np * 16 + l15] = f2b(hv);
        }
      }
    }
  }
}

// ---------------- GEMM2: 128x128, BK=64, split-K x2, STORE epilogue; 3 blocks/CU --------
__launch_bounds__(256, 3)
__global__ void gemm2_kernel(const u16* __restrict__ hbuf, const u16* __restrict__ w2t,
                             const float* __restrict__ roww,
                             const int4* __restrict__ tilemap, u16* __restrict__ part) {
  const int wg = xcd_swz(blockIdx.x, NT2 * MAXT * SPLITK2);
  const int mt = wg % MAXT;          // M fastest -> B-panel stays in XCD L2
  const int rest = wg / MAXT;
  const int nt = rest % NT2;
  const int sk = rest / NT2;         // 0..1: K chunk [sk*KCH2, (sk+1)*KCH2)
  int4 ti = tilemap[mt];
  if (ti.x < 0) return;
  const int e = ti.x, rowbase = ti.y, mvalid = ti.z;
  const int n0 = nt * BN;
  const int k0 = sk * KCH2;

  __shared__ __attribute__((aligned(128))) u16 As[BM * BK];   // 16KB
  __shared__ __attribute__((aligned(128))) u16 Bs[BN * BK];   // 16KB

  const int tid = threadIdx.x;
  const int lane = tid & 63;
  const int wv = tid >> 6;

  const int srow = tid >> 3;                         // 0..31
  const int csrc = ((tid & 7) ^ (srow & 7)) * 8;
  const u16* wb2 = w2t + (size_t)e * HID * FFN;
  const u16* gA[4]; const u16* gB[4];
  u16* lA[4]; u16* lB[4];
#pragma unroll
  for (int r = 0; r < 4; ++r) {
    int row = r * 32 + srow;
    gA[r] = hbuf + (size_t)min(rowbase + row, RTOT - 1) * FFN + k0 + csrc;
    gB[r] = wb2 + (size_t)(n0 + row) * FFN + k0 + csrc;
    lA[r] = &As[(r * 32 + wv * 8) * BK];
    lB[r] = &Bs[(r * 32 + wv * 8) * BK];
  }

  const int wm = (tid >> 7) & 1, wn = (tid >> 6) & 1;
  const int l15 = lane & 15;
  const int kg = lane >> 4;
  const int swz = l15 & 7;
  const int aBase = (wm * 64 + l15) * BK;
  const int bBase = (wn * 64 + l15) * BK;
  const int ch0 = ((0 + kg) ^ swz) * 8;
  const int ch1 = ((4 + kg) ^ swz) * 8;

  fvec4 acc[4][4] = {};

  for (int kt = 0; kt < KCH2 / BK; ++kt) {           // 28 iters
#pragma unroll
    for (int r = 0; r < 4; ++r) { gload16(gA[r], lA[r]); gA[r] += BK; }
#pragma unroll
    for (int r = 0; r < 4; ++r) { gload16(gB[r], lB[r]); gB[r] += BK; }
    __syncthreads();
    bvec8 a0[4], a1[4];
#pragma unroll
    for (int mi = 0; mi < 4; ++mi) {
      a0[mi] = *(const bvec8*)&As[aBase + mi * 16 * BK + ch0];
      a1[mi] = *(const bvec8*)&As[aBase + mi * 16 * BK + ch1];
    }
#pragma unroll
    for (int ni = 0; ni < 4; ++ni) {
      bvec8 b0 = *(const bvec8*)&Bs[bBase + ni * 16 * BK + ch0];
#pragma unroll
      for (int mi = 0; mi < 4; ++mi)
        acc[mi][ni] = __builtin_amdgcn_mfma_f32_16x16x32_bf16(a0[mi], b0, acc[mi][ni], 0, 0, 0);
      bvec8 b1 = *(const bvec8*)&Bs[bBase + ni * 16 * BK + ch1];
#pragma unroll
      for (int mi = 0; mi < 4; ++mi)
        acc[mi][ni] = __builtin_amdgcn_mfma_f32_16x16x32_bf16(a1[mi], b1, acc[mi][ni], 0, 0, 0);
    }
    __syncthreads();
  }
  // epilogue: weighted bf16 partial store (plain stores, no atomics)
  u16* pp = part + (size_t)sk * RTOT * HID;
  const int rg4 = (lane >> 4) * 4;
#pragma unroll
  for (int mi = 0; mi < 4; ++mi) {
#pragma unroll
    for (int j = 0; j < 4; ++j) {
      int ml = wm * 64 + mi * 16 + rg4 + j;
      if (ml < mvalid) {
        int r = rowbase + ml;
        float wgt = roww[r];
        u16* op = pp + (size_t)r * HID + n0 + wn * 64;
#pragma unroll
        for (int ni = 0; ni < 4; ++ni)
          op[ni * 16 + l15] = f2b(acc[mi][ni][j] * wgt);
      }
    }
  }
}

// ---------------- combine: out[t] = sum over {2 slots} x {2 K-halves} of partials -------
__global__ void combine_kernel(const u16* __restrict__ part, const int* __restrict__ tokrow,
                               float* __restrict__ out) {
  int idx = blockIdx.x * 256 + threadIdx.x;    // 8-col chunk id
  int t = idx >> 7;                            // 128 chunks per token (1024/8)
  int c = (idx & 127) * 8;
  int r0 = tokrow[2 * t], r1 = tokrow[2 * t + 1];
  const size_t sk1 = (size_t)RTOT * HID;
  bvec8 a = *(const bvec8*)(part + (size_t)r0 * HID + c);
  bvec8 b = *(const bvec8*)(part + sk1 + (size_t)r0 * HID + c);
  bvec8 d = *(const bvec8*)(part + (size_t)r1 * HID + c);
  bvec8 f = *(const bvec8*)(part + sk1 + (size_t)r1 * HID + c);
  float* dst = out + (size_t)t * HID + c;
#pragma unroll
  for (int k = 0; k < 8; ++k)
    dst[k] = (b2f((u16)a[k]) + b2f((u16)b[k])) + (b2f((u16)d[k]) + b2f((u16)f[k]));
}

// ---------------- launcher --------------------------------------------------------------
extern "C" void kernel_launch(void* const* d_in, const int* in_sizes, int n_in,
                              void* d_out, int out_size, void* d_ws, size_t ws_size,
                              hipStream_t stream) {
  (void)in_sizes; (void)n_in; (void)out_size;
  const float* x  = (const float*)d_in[0];
  const float* gw = (const float*)d_in[1];
  const float* w1 = (const float*)d_in[2];
  const float* w2 = (const float*)d_in[3];   // NOTE: dict order is w1, w2, w3
  const float* w3 = (const float*)d_in[4];
  float* out = (float*)d_out;
  float* logits = out + (size_t)T_TOK * HID;

  size_t off = 0;
  auto take = [&](size_t b) { size_t o = off; off += (b + 255) & ~(size_t)255; return o; };
  size_t o_xb   = take((size_t)T_TOK * HID * 2);           // x bf16
  size_t o_wt   = take((size_t)NEXP * FFI * HID * 2);      // Bi; later: w2t (front) + part (back)
  size_t o_hb   = take((size_t)RTOT * FFN * 2);            // h bf16
  size_t o_rmap = take((size_t)RTOT * 4);
  size_t o_rw   = take((size_t)RTOT * 4);
  size_t o_tid  = take((size_t)RTOT * 4);
  size_t o_tw   = take((size_t)RTOT * 4);
  size_t o_trow = take((size_t)RTOT * 4);
  size_t o_cnt  = take(4 * NEXP);
  size_t o_ofs  = take(4 * (NEXP + 1));
  size_t o_cur  = take(4 * NEXP);
  size_t o_tmap = take(MAXT * 16);
  size_t total = off;

  if (ws_size < total) {
    hipMemsetAsync(d_out, 0, (size_t)T_TOK * HID * sizeof(float), stream);
    router_kernel<<<T_TOK / 4, 256, 0, stream>>>(x, gw, logits, nullptr, nullptr, nullptr,
                                                 nullptr, 0);
    return;
  }

  char* w = (char*)d_ws;
  u16* xb   = (u16*)(w + o_xb);
  u16* bi   = (u16*)(w + o_wt);
  u16* w2t  = bi;                                   // front 56MB, reused after gemm1
  u16* part = bi + (size_t)NEXP * HID * FFN;        // back 58.7MB free region: 2x16.7MB
  u16* hb   = (u16*)(w + o_hb);
  int*   rmap = (int*)(w + o_rmap);
  float* rw   = (float*)(w + o_rw);
  int*   tkid = (int*)(w + o_tid);
  float* tkw  = (float*)(w + o_tw);
  int*   trow = (int*)(w + o_trow);
  int*   cnt  = (int*)(w + o_cnt);
  int*   ofs  = (int*)(w + o_ofs);
  int*   cur  = (int*)(w + o_cur);
  int4*  tmap = (int4*)(w + o_tmap);

  hipMemsetAsync(cnt, 0, 4 * NEXP, stream);
  router_kernel<<<T_TOK / 4, 256, 0, stream>>>(x, gw, logits, tkid, tkw, cnt, xb, 1);
  scan_kernel<<<1, 64, 0, stream>>>(cnt, ofs, cur, tmap);
  scatter_kernel<<<RTOT / 256, 256, 0, stream>>>(tkid, tkw, ofs, cur, rmap, rw, trow);
  transpose_cast_dual_kernel<<<dim3(FFN / 64, HID / 64, 2 * NEXP), 256, 0, stream>>>(w1, w3, bi);
  gemm1_kernel<<<NT1 * MAXT, 256, 0, stream>>>(xb, bi, rmap, tmap, hb);
  transpose_cast_w2_kernel<<<dim3(HID / 64, FFN / 64, NEXP), 256, 0, stream>>>(w2, w2t);
  gemm2_kernel<<<NT2 * MAXT * SPLITK2, 256, 0, stream>>>(hb, w2t, rw, tmap, part);
  combine_kernel<<<T_TOK * HID / 8 / 256, 256, 0, stream>>>(part, trow, out);
}

// Round 14
// 384.845 us; speedup vs baseline: 4.8023x; 1.2643x over previous
//
#include <hip/hip_runtime.h>
#include <hip/hip_bf16.h>
#include <cstdint>
#include <cstddef>

#define T_TOK 4096
#define HID   1024
#define FFN   3584
#define FFI   (2 * FFN)     // interleaved g/u columns: 7168
#define NEXP  8
#define RTOT  (T_TOK * 2)   // total (token, slot) rows = T * top_k
#define MAXT  72            // max 128-row M-tiles: floor(8192/128)+7=71, +1 slack
#define BM 128
#define BN 128
#define BK 64
#define NT1 (FFI / BN)      // 56 N-tiles for gemm1 (interleaved)
#define NT2 (HID / BN)      // 8 N-tiles for gemm2
#define SPLITK2 2           // gemm2 split-K (3584 -> 2 x 1792); partials stored, no atomics
#define KCH2 (FFN / SPLITK2)
#define CPAD 32             // counter padding: one 128B cacheline per expert

typedef __attribute__((ext_vector_type(8))) short bvec8;   // 8 x bf16 (4 VGPR) MFMA operand
typedef __attribute__((ext_vector_type(4))) short bvec4;
typedef __attribute__((ext_vector_type(4))) float fvec4;   // MFMA accumulator
typedef unsigned short u16;

__device__ __forceinline__ u16 f2b(float f) {
  __bf16 b = (__bf16)f;                 // RNE convert
  return __builtin_bit_cast(u16, b);
}
__device__ __forceinline__ float b2f(u16 u) {
  unsigned v = (unsigned)u << 16;       // bf16 -> f32 exact
  return __builtin_bit_cast(float, v);
}

// async global->LDS, 16B per lane. LDS dest must be wave-uniform base (HW adds lane*16).
__device__ __forceinline__ void gload16(const u16* g, u16* l) {
  __builtin_amdgcn_global_load_lds((const __attribute__((address_space(1))) void*)g,
                                   (__attribute__((address_space(3))) void*)l, 16, 0, 0);
}

// bijective XCD swizzle (m204): contiguous chunk of work per XCD
__device__ __forceinline__ int xcd_swz(int bid, int nwg) {
  int q = nwg >> 3, r = nwg & 7;
  int xcd = bid & 7, sub = bid >> 3;
  return (xcd < r ? xcd * (q + 1) : r * (q + 1) + (xcd - r) * q) + sub;
}

// ---------------- router: logits (fp32), top-2, combine weights, counts, + x->bf16 ------
__global__ void router_kernel(const float* __restrict__ x, const float* __restrict__ gw,
                              float* __restrict__ logits, int* __restrict__ tk_id,
                              float* __restrict__ tk_w, int* __restrict__ counts,
                              u16* __restrict__ xb, int full) {
  const int lane = threadIdx.x & 63;
  const int wid  = threadIdx.x >> 6;
  const int t = blockIdx.x * 4 + wid;          // one token per wave
  const float4* xr = (const float4*)(x + (size_t)t * HID);
  float acc[NEXP] = {0.f, 0.f, 0.f, 0.f, 0.f, 0.f, 0.f, 0.f};
#pragma unroll
  for (int it = 0; it < 4; ++it) {
    int k4 = it * 64 + lane;                   // float4 index, covers H/4 = 256
    float4 xv = xr[k4];
    if (xb) {                                  // fused bf16 cast of x
      bvec4 o;
      o[0] = (short)f2b(xv.x); o[1] = (short)f2b(xv.y);
      o[2] = (short)f2b(xv.z); o[3] = (short)f2b(xv.w);
      *(bvec4*)(xb + (size_t)t * HID + k4 * 4) = o;
    }
    const float* gp = gw + (size_t)k4 * 4 * NEXP;
    float xs[4] = {xv.x, xv.y, xv.z, xv.w};
#pragma unroll
    for (int kk = 0; kk < 4; ++kk) {
      float4 ga = ((const float4*)(gp + kk * NEXP))[0];
      float4 gb = ((const float4*)(gp + kk * NEXP))[1];
      acc[0] += xs[kk] * ga.x; acc[1] += xs[kk] * ga.y;
      acc[2] += xs[kk] * ga.z; acc[3] += xs[kk] * ga.w;
      acc[4] += xs[kk] * gb.x; acc[5] += xs[kk] * gb.y;
      acc[6] += xs[kk] * gb.z; acc[7] += xs[kk] * gb.w;
    }
  }
#pragma unroll
  for (int off = 32; off > 0; off >>= 1) {
#pragma unroll
    for (int e = 0; e < NEXP; ++e) acc[e] += __shfl_xor(acc[e], off, 64);
  }
  if (lane < NEXP) logits[(size_t)t * NEXP + lane] = acc[lane];
  if (full && lane == 0) {
    int e0 = 0; float l0 = acc[0];
#pragma unroll
    for (int e = 1; e < NEXP; ++e) if (acc[e] > l0) { l0 = acc[e]; e0 = e; }
    int e1 = -1; float l1 = -3.4e38f;
#pragma unroll
    for (int e = 0; e < NEXP; ++e) if (e != e0 && acc[e] > l1) { l1 = acc[e]; e1 = e; }
    float w0 = 1.f / (1.f + expf(l1 - l0));
    float w1 = 1.f - w0;
    tk_id[t * 2 + 0] = e0; tk_id[t * 2 + 1] = e1;
    tk_w[t * 2 + 0] = w0;  tk_w[t * 2 + 1] = w1;
    atomicAdd(&counts[e0 * CPAD], 1); atomicAdd(&counts[e1 * CPAD], 1);  // padded: 8 L2 channels
  }
}

// ---------------- scan: offsets + tile map, parallel (counts/cursors are CPAD-strided) --
__global__ void scan_kernel(const int* __restrict__ counts, int* __restrict__ offsets,
                            int* __restrict__ cursors, int4* __restrict__ tilemap) {
  __shared__ int c[NEXP];
  __shared__ int tbase[NEXP + 1];
  const int t = threadIdx.x;
  if (t < NEXP) c[t] = counts[t * CPAD];
  __syncthreads();
  if (t < NEXP) {
    int off = 0, tiles = 0;
    for (int e = 0; e < t; ++e) { off += c[e]; tiles += (c[e] + BM - 1) / BM; }
    offsets[t] = off; cursors[t * CPAD] = 0;
    if (t == NEXP - 1) {
      offsets[NEXP] = off + c[t];
      tbase[NEXP] = tiles + (c[t] + BM - 1) / BM;
    }
    tbase[t] = tiles;
    const int cc = c[t];
    for (int tm = 0; tm * BM < cc; ++tm)
      tilemap[tiles + tm] = make_int4(t, off + tm * BM, min(BM, cc - tm * BM), 0);
  }
  __syncthreads();
  for (int i = tbase[NEXP] + t; i < MAXT; i += 64)
    tilemap[i] = make_int4(-1, 0, 0, 0);
}

// ---------------- scatter: wave-aggregated (1 atomic per wave per expert, not per item) -
__global__ void scatter_kernel(const int* __restrict__ tk_id, const float* __restrict__ tk_w,
                               const int* __restrict__ offsets, int* __restrict__ cursors,
                               int* __restrict__ rowmap, float* __restrict__ roww,
                               int* __restrict__ tokrow) {
  int i = blockIdx.x * 256 + threadIdx.x;      // 0 .. RTOT-1
  int t = i >> 1;
  int e = tk_id[i]; float w = tk_w[i];
  const int lane = threadIdx.x & 63;
  const unsigned long long lt = (lane == 63) ? ~0ull >> 1 : (1ull << lane) - 1ull;
  int base = 0, rank = 0;
#pragma unroll
  for (int ex = 0; ex < NEXP; ++ex) {          // wave-uniform loop
    unsigned long long m = __ballot(e == ex);
    if (e == ex) {
      int cnt = __popcll(m);
      int leader = __ffsll((long long)m) - 1;  // uniform within group
      int b = 0;
      if (lane == leader) b = atomicAdd(&cursors[ex * CPAD], cnt);
      b = __shfl(b, leader, 64);
      base = b; rank = __popcll(m & lt);
    }
  }
  int r = offsets[e] + base + rank;
  rowmap[r] = t; roww[r] = w;
  tokrow[i] = r;                               // slot i of token t lives at row r
}

// ---------------- transpose-cast (conflict-light): fp32 [R][C] 64x64 tile -> bf16 ------
__global__ void transpose_cast_dual_kernel(const float* __restrict__ w1,
                                           const float* __restrict__ w3,
                                           u16* __restrict__ bi) {
  __shared__ __attribute__((aligned(16))) u16 tile[64 * 72];
  const int z = blockIdx.z, e = z >> 1, half = z & 1;
  const float* src = (half ? w3 : w1) + (size_t)e * HID * FFN;   // [HID][FFN]
  u16* dst = bi + (size_t)e * FFI * HID;
  const int c0 = blockIdx.x * 64, r0 = blockIdx.y * 64;
  const int t = threadIdx.x;
  const int m = t & 15;             // col-group (cols 4m..4m+3)
  const int g = t >> 4;             // row-group (rows 4g..4g+3)
  u16 v[4][4];                      // v[i][j] = elem(row 4g+i, col 4m+j)
#pragma unroll
  for (int i = 0; i < 4; ++i) {
    float4 q = *(const float4*)(src + (size_t)(r0 + 4 * g + i) * FFN + c0 + 4 * m);
    v[i][0] = f2b(q.x); v[i][1] = f2b(q.y); v[i][2] = f2b(q.z); v[i][3] = f2b(q.w);
  }
  const int phys = (g ^ ((m & 3) << 2)) * 4;   // swizzled chunk offset (u16)
#pragma unroll
  for (int j = 0; j < 4; ++j) {
    int c = 4 * m + j;
    bvec4 o; o[0] = (short)v[0][j]; o[1] = (short)v[1][j];
    o[2] = (short)v[2][j]; o[3] = (short)v[3][j];
    *(bvec4*)&tile[c * 72 + phys] = o;
  }
  __syncthreads();
  const int cl = t >> 2;            // output row (source col) 0..63
  const int q  = t & 3;             // 16-elem r-group
  const int base = ((q ^ ((cl >> 2) & 3)) << 4);    // swizzled 16-u16 group offset
  bvec8 ra = *(const bvec8*)&tile[cl * 72 + base];
  bvec8 rb = *(const bvec8*)&tile[cl * 72 + base + 8];
  const int orow = (c0 << 1) + ((cl >> 4) << 5) + (cl & 15) + (half << 4);
  u16* dp = dst + (size_t)orow * HID + r0 + 16 * q;
  *(bvec8*)(dp + 0) = ra;
  *(bvec8*)(dp + 8) = rb;
}

// ---------------- transpose-cast w2 [E][FFN][HID] -> w2t [E][HID][FFN] (same scheme) ----
__global__ void transpose_cast_w2_kernel(const float* __restrict__ w2, u16* __restrict__ w2t) {
  __shared__ __attribute__((aligned(16))) u16 tile[64 * 72];
  const int e = blockIdx.z;
  const float* src = w2 + (size_t)e * FFN * HID;   // [FFN][HID]
  u16* dst = w2t + (size_t)e * HID * FFN;          // [HID][FFN]
  const int c0 = blockIdx.x * 64, r0 = blockIdx.y * 64;
  const int t = threadIdx.x;
  const int m = t & 15;
  const int g = t >> 4;
  u16 v[4][4];
#pragma unroll
  for (int i = 0; i < 4; ++i) {
    float4 q = *(const float4*)(src + (size_t)(r0 + 4 * g + i) * HID + c0 + 4 * m);
    v[i][0] = f2b(q.x); v[i][1] = f2b(q.y); v[i][2] = f2b(q.z); v[i][3] = f2b(q.w);
  }
  const int phys = (g ^ ((m & 3) << 2)) * 4;
#pragma unroll
  for (int j = 0; j < 4; ++j) {
    int c = 4 * m + j;
    bvec4 o; o[0] = (short)v[0][j]; o[1] = (short)v[1][j];
    o[2] = (short)v[2][j]; o[3] = (short)v[3][j];
    *(bvec4*)&tile[c * 72 + phys] = o;
  }
  __syncthreads();
  const int cl = t >> 2;
  const int q  = t & 3;
  const int base = ((q ^ ((cl >> 2) & 3)) << 4);
  bvec8 ra = *(const bvec8*)&tile[cl * 72 + base];
  bvec8 rb = *(const bvec8*)&tile[cl * 72 + base + 8];
  u16* dp = dst + (size_t)(c0 + cl) * FFN + r0 + 16 * q;
  *(bvec8*)(dp + 0) = ra;
  *(bvec8*)(dp + 8) = rb;
}

// ---------------- GEMM1: 128x128, BK=64, R6 2-barrier structure; 3 blocks/CU ------------
// NOTE (R11 lesson): unified VGPR+AGPR need ≈136 regs -> 3 waves/EU (cap 170) is the max.
__launch_bounds__(256, 3)
__global__ void gemm1_kernel(const u16* __restrict__ xb, const u16* __restrict__ bi,
                             const int* __restrict__ rowmap,
                             const int4* __restrict__ tilemap, u16* __restrict__ hbuf) {
  const int wg = xcd_swz(blockIdx.x, NT1 * MAXT);
  const int mt = wg % MAXT;          // M fastest within an XCD chunk -> B-panel L2 reuse
  const int nt = wg / MAXT;
  int4 ti = tilemap[mt];
  if (ti.x < 0) return;
  const int e = ti.x, rowbase = ti.y, mvalid = ti.z;
  const int n0 = nt * BN;

  __shared__ __attribute__((aligned(128))) u16 As[BM * BK];   // 16KB
  __shared__ __attribute__((aligned(128))) u16 Bs[BN * BK];   // 16KB

  const int tid = threadIdx.x;
  const int lane = tid & 63;
  const int wv = tid >> 6;

  const int srow = tid >> 3;                         // 0..31
  const int csrc = ((tid & 7) ^ (srow & 7)) * 8;     // pre-swizzled source chunk (elems)
  const u16* wb = bi + (size_t)e * FFI * HID;
  const u16* gA[4]; const u16* gB[4];
  u16* lA[4]; u16* lB[4];
#pragma unroll
  for (int r = 0; r < 4; ++r) {
    int row = r * 32 + srow;
    int tok = rowmap[min(rowbase + row, RTOT - 1)];
    gA[r] = xb + (size_t)tok * HID + csrc;
    gB[r] = wb + (size_t)(n0 + row) * HID + csrc;
    lA[r] = &As[(r * 32 + wv * 8) * BK];             // wave-uniform dests
    lB[r] = &Bs[(r * 32 + wv * 8) * BK];
  }

  const int wm = (tid >> 7) & 1, wn = (tid >> 6) & 1;   // 2x2 waves, 64x64 each
  const int l15 = lane & 15;
  const int kg = lane >> 4;                          // 0..3
  const int swz = l15 & 7;
  const int aBase = (wm * 64 + l15) * BK;
  const int bBase = (wn * 64 + l15) * BK;
  const int ch0 = ((0 + kg) ^ swz) * 8;              // ks=0 phys chunk (elems)
  const int ch1 = ((4 + kg) ^ swz) * 8;              // ks=1

  fvec4 acc[4][4] = {};

  for (int kt = 0; kt < HID / BK; ++kt) {            // 16 iters
#pragma unroll
    for (int r = 0; r < 4; ++r) { gload16(gA[r], lA[r]); gA[r] += BK; }
#pragma unroll
    for (int r = 0; r < 4; ++r) { gload16(gB[r], lB[r]); gB[r] += BK; }
    __syncthreads();
    bvec8 a0[4], a1[4];
#pragma unroll
    for (int mi = 0; mi < 4; ++mi) {
      a0[mi] = *(const bvec8*)&As[aBase + mi * 16 * BK + ch0];
      a1[mi] = *(const bvec8*)&As[aBase + mi * 16 * BK + ch1];
    }
#pragma unroll
    for (int ni = 0; ni < 4; ++ni) {
      bvec8 b0 = *(const bvec8*)&Bs[bBase + ni * 16 * BK + ch0];
#pragma unroll
      for (int mi = 0; mi < 4; ++mi)
        acc[mi][ni] = __builtin_amdgcn_mfma_f32_16x16x32_bf16(a0[mi], b0, acc[mi][ni], 0, 0, 0);
      bvec8 b1 = *(const bvec8*)&Bs[bBase + ni * 16 * BK + ch1];
#pragma unroll
      for (int mi = 0; mi < 4; ++mi)
        acc[mi][ni] = __builtin_amdgcn_mfma_f32_16x16x32_bf16(a1[mi], b1, acc[mi][ni], 0, 0, 0);
    }
    __syncthreads();
  }
  // epilogue: pair ni (even=g, odd=u): h = silu(g) * u, bf16
  const int rg4 = (lane >> 4) * 4;
#pragma unroll
  for (int mi = 0; mi < 4; ++mi) {
#pragma unroll
    for (int j = 0; j < 4; ++j) {
      int ml = wm * 64 + mi * 16 + rg4 + j;
      if (ml < mvalid) {
        size_t rowoff = (size_t)(rowbase + ml) * FFN + ((n0 + wn * 64) >> 1);
#pragma unroll
        for (int np = 0; np < 2; ++np) {
          float g = acc[mi][2 * np][j], u = acc[mi][2 * np + 1][j];
          float hv = (g / (1.f + expf(-g))) * u;
          hbuf[rowoff + np * 16 + l15] = f2b(hv);
        }
      }
    }
  }
}

// ---------------- GEMM2: 128x128, BK=64, split-K x2, STORE epilogue; 3 blocks/CU --------
__launch_bounds__(256, 3)
__global__ void gemm2_kernel(const u16* __restrict__ hbuf, const u16* __restrict__ w2t,
                             const float* __restrict__ roww,
                             const int4* __restrict__ tilemap, u16* __restrict__ part) {
  const int wg = xcd_swz(blockIdx.x, NT2 * MAXT * SPLITK2);
  const int mt = wg % MAXT;          // M fastest -> B-panel stays in XCD L2
  const int rest = wg / MAXT;
  const int nt = rest % NT2;
  const int sk = rest / NT2;         // 0..1: K chunk [sk*KCH2, (sk+1)*KCH2)
  int4 ti = tilemap[mt];
  if (ti.x < 0) return;
  const int e = ti.x, rowbase = ti.y, mvalid = ti.z;
  const int n0 = nt * BN;
  const int k0 = sk * KCH2;

  __shared__ __attribute__((aligned(128))) u16 As[BM * BK];   // 16KB
  __shared__ __attribute__((aligned(128))) u16 Bs[BN * BK];   // 16KB

  const int tid = threadIdx.x;
  const int lane = tid & 63;
  const int wv = tid >> 6;

  const int srow = tid >> 3;                         // 0..31
  const int csrc = ((tid & 7) ^ (srow & 7)) * 8;
  const u16* wb2 = w2t + (size_t)e * HID * FFN;
  const u16* gA[4]; const u16* gB[4];
  u16* lA[4]; u16* lB[4];
#pragma unroll
  for (int r = 0; r < 4; ++r) {
    int row = r * 32 + srow;
    gA[r] = hbuf + (size_t)min(rowbase + row, RTOT - 1) * FFN + k0 + csrc;
    gB[r] = wb2 + (size_t)(n0 + row) * FFN + k0 + csrc;
    lA[r] = &As[(r * 32 + wv * 8) * BK];
    lB[r] = &Bs[(r * 32 + wv * 8) * BK];
  }

  const int wm = (tid >> 7) & 1, wn = (tid >> 6) & 1;
  const int l15 = lane & 15;
  const int kg = lane >> 4;
  const int swz = l15 & 7;
  const int aBase = (wm * 64 + l15) * BK;
  const int bBase = (wn * 64 + l15) * BK;
  const int ch0 = ((0 + kg) ^ swz) * 8;
  const int ch1 = ((4 + kg) ^ swz) * 8;

  fvec4 acc[4][4] = {};

  for (int kt = 0; kt < KCH2 / BK; ++kt) {           // 28 iters
#pragma unroll
    for (int r = 0; r < 4; ++r) { gload16(gA[r], lA[r]); gA[r] += BK; }
#pragma unroll
    for (int r = 0; r < 4; ++r) { gload16(gB[r], lB[r]); gB[r] += BK; }
    __syncthreads();
    bvec8 a0[4], a1[4];
#pragma unroll
    for (int mi = 0; mi < 4; ++mi) {
      a0[mi] = *(const bvec8*)&As[aBase + mi * 16 * BK + ch0];
      a1[mi] = *(const bvec8*)&As[aBase + mi * 16 * BK + ch1];
    }
#pragma unroll
    for (int ni = 0; ni < 4; ++ni) {
      bvec8 b0 = *(const bvec8*)&Bs[bBase + ni * 16 * BK + ch0];
#pragma unroll
      for (int mi = 0; mi < 4; ++mi)
        acc[mi][ni] = __builtin_amdgcn_mfma_f32_16x16x32_bf16(a0[mi], b0, acc[mi][ni], 0, 0, 0);
      bvec8 b1 = *(const bvec8*)&Bs[bBase + ni * 16 * BK + ch1];
#pragma unroll
      for (int mi = 0; mi < 4; ++mi)
        acc[mi][ni] = __builtin_amdgcn_mfma_f32_16x16x32_bf16(a1[mi], b1, acc[mi][ni], 0, 0, 0);
    }
    __syncthreads();
  }
  // epilogue: weighted bf16 partial store (plain stores, no atomics)
  u16* pp = part + (size_t)sk * RTOT * HID;
  const int rg4 = (lane >> 4) * 4;
#pragma unroll
  for (int mi = 0; mi < 4; ++mi) {
#pragma unroll
    for (int j = 0; j < 4; ++j) {
      int ml = wm * 64 + mi * 16 + rg4 + j;
      if (ml < mvalid) {
        int r = rowbase + ml;
        float wgt = roww[r];
        u16* op = pp + (size_t)r * HID + n0 + wn * 64;
#pragma unroll
        for (int ni = 0; ni < 4; ++ni)
          op[ni * 16 + l15] = f2b(acc[mi][ni][j] * wgt);
      }
    }
  }
}

// ---------------- combine: out[t] = sum over {2 slots} x {2 K-halves} of partials -------
__global__ void combine_kernel(const u16* __restrict__ part, const int* __restrict__ tokrow,
                               float* __restrict__ out) {
  int idx = blockIdx.x * 256 + threadIdx.x;    // 8-col chunk id
  int t = idx >> 7;                            // 128 chunks per token (1024/8)
  int c = (idx & 127) * 8;
  int r0 = tokrow[2 * t], r1 = tokrow[2 * t + 1];
  const size_t sk1 = (size_t)RTOT * HID;
  bvec8 a = *(const bvec8*)(part + (size_t)r0 * HID + c);
  bvec8 b = *(const bvec8*)(part + sk1 + (size_t)r0 * HID + c);
  bvec8 d = *(const bvec8*)(part + (size_t)r1 * HID + c);
  bvec8 f = *(const bvec8*)(part + sk1 + (size_t)r1 * HID + c);
  float* dst = out + (size_t)t * HID + c;
#pragma unroll
  for (int k = 0; k < 8; ++k)
    dst[k] = (b2f((u16)a[k]) + b2f((u16)b[k])) + (b2f((u16)d[k]) + b2f((u16)f[k]));
}

// ---------------- launcher --------------------------------------------------------------
extern "C" void kernel_launch(void* const* d_in, const int* in_sizes, int n_in,
                              void* d_out, int out_size, void* d_ws, size_t ws_size,
                              hipStream_t stream) {
  (void)in_sizes; (void)n_in; (void)out_size;
  const float* x  = (const float*)d_in[0];
  const float* gw = (const float*)d_in[1];
  const float* w1 = (const float*)d_in[2];
  const float* w2 = (const float*)d_in[3];   // NOTE: dict order is w1, w2, w3
  const float* w3 = (const float*)d_in[4];
  float* out = (float*)d_out;
  float* logits = out + (size_t)T_TOK * HID;

  size_t off = 0;
  auto take = [&](size_t b) { size_t o = off; off += (b + 255) & ~(size_t)255; return o; };
  size_t o_xb   = take((size_t)T_TOK * HID * 2);           // x bf16
  size_t o_wt   = take((size_t)NEXP * FFI * HID * 2);      // Bi; later: w2t (front) + part (back)
  size_t o_hb   = take((size_t)RTOT * FFN * 2);            // h bf16
  size_t o_rmap = take((size_t)RTOT * 4);
  size_t o_rw   = take((size_t)RTOT * 4);
  size_t o_tid  = take((size_t)RTOT * 4);
  size_t o_tw   = take((size_t)RTOT * 4);
  size_t o_trow = take((size_t)RTOT * 4);
  size_t o_cnt  = take(4 * NEXP * CPAD);
  size_t o_ofs  = take(4 * (NEXP + 1));
  size_t o_cur  = take(4 * NEXP * CPAD);
  size_t o_tmap = take(MAXT * 16);
  size_t total = off;

  if (ws_size < total) {
    hipMemsetAsync(d_out, 0, (size_t)T_TOK * HID * sizeof(float), stream);
    router_kernel<<<T_TOK / 4, 256, 0, stream>>>(x, gw, logits, nullptr, nullptr, nullptr,
                                                 nullptr, 0);
    return;
  }

  char* w = (char*)d_ws;
  u16* xb   = (u16*)(w + o_xb);
  u16* bi   = (u16*)(w + o_wt);
  u16* w2t  = bi;                                   // front 56MB, reused after gemm1
  u16* part = bi + (size_t)NEXP * HID * FFN;        // back 58.7MB free region: 2x16.7MB
  u16* hb   = (u16*)(w + o_hb);
  int*   rmap = (int*)(w + o_rmap);
  float* rw   = (float*)(w + o_rw);
  int*   tkid = (int*)(w + o_tid);
  float* tkw  = (float*)(w + o_tw);
  int*   trow = (int*)(w + o_trow);
  int*   cnt  = (int*)(w + o_cnt);
  int*   ofs  = (int*)(w + o_ofs);
  int*   cur  = (int*)(w + o_cur);
  int4*  tmap = (int4*)(w + o_tmap);

  hipMemsetAsync(cnt, 0, 4 * NEXP * CPAD, stream);
  router_kernel<<<T_TOK / 4, 256, 0, stream>>>(x, gw, logits, tkid, tkw, cnt, xb, 1);
  scan_kernel<<<1, 64, 0, stream>>>(cnt, ofs, cur, tmap);
  scatter_kernel<<<RTOT / 256, 256, 0, stream>>>(tkid, tkw, ofs, cur, rmap, rw, trow);
  transpose_cast_dual_kernel<<<dim3(FFN / 64, HID / 64, 2 * NEXP), 256, 0, stream>>>(w1, w3, bi);
  gemm1_kernel<<<NT1 * MAXT, 256, 0, stream>>>(xb, bi, rmap, tmap, hb);
  transpose_cast_w2_kernel<<<dim3(HID / 64, FFN / 64, NEXP), 256, 0, stream>>>(w2, w2t);
  gemm2_kernel<<<NT2 * MAXT * SPLITK2, 256, 0, stream>>>(hb, w2t, rw, tmap, part);
  combine_kernel<<<T_TOK * HID / 8 / 256, 256, 0, stream>>>(part, trow, out);
}

// Round 15
// 384.642 us; speedup vs baseline: 4.8048x; 1.0005x over previous
//
#include <hip/hip_runtime.h>
#include <hip/hip_bf16.h>
#include <cstdint>
#include <cstddef>

#define T_TOK 4096
#define HID   1024
#define FFN   3584
#define FFI   (2 * FFN)     // interleaved g/u columns: 7168
#define NEXP  8
#define RTOT  (T_TOK * 2)   // total (token, slot) rows = T * top_k
#define MAXT  72            // max 128-row M-tiles: floor(8192/128)+7=71, +1 slack
#define BM 128
#define BN 128
#define BK 64
#define NT1 (FFI / BN)      // 56 N-tiles for gemm1 (interleaved)
#define NT2 (HID / BN)      // 8 N-tiles for gemm2
#define SPLITK2 2           // gemm2 split-K (3584 -> 2 x 1792); partials stored, no atomics
#define KCH2 (FFN / SPLITK2)
#define CPAD 32             // counter padding: one cacheline per expert (R14: -102us)
#define G1BLKS (NT1 * MAXT)            // 4032 gemm1 blocks
#define W2TBLKS ((HID/64)*(FFN/64)*NEXP)  // 7168 w2-transpose blocks
#define RTRBLKS (T_TOK / 4)            // 1024 router blocks
#define DTBLKS  ((FFN/64)*(HID/64)*2*NEXP) // 14336 dual-transpose blocks

typedef __attribute__((ext_vector_type(8))) short bvec8;   // 8 x bf16 (4 VGPR) MFMA operand
typedef __attribute__((ext_vector_type(4))) short bvec4;
typedef __attribute__((ext_vector_type(4))) float fvec4;   // MFMA accumulator
typedef unsigned short u16;

__device__ __forceinline__ u16 f2b(float f) {
  __bf16 b = (__bf16)f;                 // RNE convert
  return __builtin_bit_cast(u16, b);
}
__device__ __forceinline__ float b2f(u16 u) {
  unsigned v = (unsigned)u << 16;       // bf16 -> f32 exact
  return __builtin_bit_cast(float, v);
}

// async global->LDS, 16B per lane. LDS dest must be wave-uniform base (HW adds lane*16).
__device__ __forceinline__ void gload16(const u16* g, u16* l) {
  __builtin_amdgcn_global_load_lds((const __attribute__((address_space(1))) void*)g,
                                   (__attribute__((address_space(3))) void*)l, 16, 0, 0);
}

// bijective XCD swizzle (m204): contiguous chunk of work per XCD
__device__ __forceinline__ int xcd_swz(int bid, int nwg) {
  int q = nwg >> 3, r = nwg & 7;
  int xcd = bid & 7, sub = bid >> 3;
  return (xcd < r ? xcd * (q + 1) : r * (q + 1) + (xcd - r) * q) + sub;
}

// ================= device bodies (shared by standalone + fused kernels) =================

__device__ void router_body(const float* __restrict__ x, const float* __restrict__ gw,
                            float* __restrict__ logits, int* __restrict__ tk_id,
                            float* __restrict__ tk_w, int* __restrict__ counts,
                            u16* __restrict__ xb, int blk, int tid) {
  const int lane = tid & 63;
  const int wid  = tid >> 6;
  const int t = blk * 4 + wid;                 // one token per wave
  const float4* xr = (const float4*)(x + (size_t)t * HID);
  float acc[NEXP] = {0.f, 0.f, 0.f, 0.f, 0.f, 0.f, 0.f, 0.f};
#pragma unroll
  for (int it = 0; it < 4; ++it) {
    int k4 = it * 64 + lane;
    float4 xv = xr[k4];
    if (xb) {
      bvec4 o;
      o[0] = (short)f2b(xv.x); o[1] = (short)f2b(xv.y);
      o[2] = (short)f2b(xv.z); o[3] = (short)f2b(xv.w);
      *(bvec4*)(xb + (size_t)t * HID + k4 * 4) = o;
    }
    const float* gp = gw + (size_t)k4 * 4 * NEXP;
    float xs[4] = {xv.x, xv.y, xv.z, xv.w};
#pragma unroll
    for (int kk = 0; kk < 4; ++kk) {
      float4 ga = ((const float4*)(gp + kk * NEXP))[0];
      float4 gb = ((const float4*)(gp + kk * NEXP))[1];
      acc[0] += xs[kk] * ga.x; acc[1] += xs[kk] * ga.y;
      acc[2] += xs[kk] * ga.z; acc[3] += xs[kk] * ga.w;
      acc[4] += xs[kk] * gb.x; acc[5] += xs[kk] * gb.y;
      acc[6] += xs[kk] * gb.z; acc[7] += xs[kk] * gb.w;
    }
  }
#pragma unroll
  for (int off = 32; off > 0; off >>= 1) {
#pragma unroll
    for (int e = 0; e < NEXP; ++e) acc[e] += __shfl_xor(acc[e], off, 64);
  }
  if (lane < NEXP) logits[(size_t)t * NEXP + lane] = acc[lane];
  if (tk_id && lane == 0) {
    int e0 = 0; float l0 = acc[0];
#pragma unroll
    for (int e = 1; e < NEXP; ++e) if (acc[e] > l0) { l0 = acc[e]; e0 = e; }
    int e1 = -1; float l1 = -3.4e38f;
#pragma unroll
    for (int e = 0; e < NEXP; ++e) if (e != e0 && acc[e] > l1) { l1 = acc[e]; e1 = e; }
    float w0 = 1.f / (1.f + expf(l1 - l0));
    float w1 = 1.f - w0;
    tk_id[t * 2 + 0] = e0; tk_id[t * 2 + 1] = e1;
    tk_w[t * 2 + 0] = w0;  tk_w[t * 2 + 1] = w1;
    atomicAdd(&counts[e0 * CPAD], 1); atomicAdd(&counts[e1 * CPAD], 1);
  }
}

__device__ void dualT_body(const float* __restrict__ w1, const float* __restrict__ w3,
                           u16* __restrict__ bi, int bx, int by, int bz, int t,
                           u16* __restrict__ tile) {           // tile: 64*72 u16
  const int e = bz >> 1, half = bz & 1;
  const float* src = (half ? w3 : w1) + (size_t)e * HID * FFN;   // [HID][FFN]
  u16* dst = bi + (size_t)e * FFI * HID;
  const int c0 = bx * 64, r0 = by * 64;
  const int m = t & 15;
  const int g = t >> 4;
  u16 v[4][4];
#pragma unroll
  for (int i = 0; i < 4; ++i) {
    float4 q = *(const float4*)(src + (size_t)(r0 + 4 * g + i) * FFN + c0 + 4 * m);
    v[i][0] = f2b(q.x); v[i][1] = f2b(q.y); v[i][2] = f2b(q.z); v[i][3] = f2b(q.w);
  }
  const int phys = (g ^ ((m & 3) << 2)) * 4;
#pragma unroll
  for (int j = 0; j < 4; ++j) {
    int c = 4 * m + j;
    bvec4 o; o[0] = (short)v[0][j]; o[1] = (short)v[1][j];
    o[2] = (short)v[2][j]; o[3] = (short)v[3][j];
    *(bvec4*)&tile[c * 72 + phys] = o;
  }
  __syncthreads();
  const int cl = t >> 2;
  const int q  = t & 3;
  const int base = ((q ^ ((cl >> 2) & 3)) << 4);
  bvec8 ra = *(const bvec8*)&tile[cl * 72 + base];
  bvec8 rb = *(const bvec8*)&tile[cl * 72 + base + 8];
  const int orow = (c0 << 1) + ((cl >> 4) << 5) + (cl & 15) + (half << 4);
  u16* dp = dst + (size_t)orow * HID + r0 + 16 * q;
  *(bvec8*)(dp + 0) = ra;
  *(bvec8*)(dp + 8) = rb;
}

__device__ void w2T_body(const float* __restrict__ w2, u16* __restrict__ w2t,
                         int bx, int by, int e, int t, u16* __restrict__ tile) {
  const float* src = w2 + (size_t)e * FFN * HID;   // [FFN][HID]
  u16* dst = w2t + (size_t)e * HID * FFN;          // [HID][FFN]
  const int c0 = bx * 64, r0 = by * 64;
  const int m = t & 15;
  const int g = t >> 4;
  u16 v[4][4];
#pragma unroll
  for (int i = 0; i < 4; ++i) {
    float4 q = *(const float4*)(src + (size_t)(r0 + 4 * g + i) * HID + c0 + 4 * m);
    v[i][0] = f2b(q.x); v[i][1] = f2b(q.y); v[i][2] = f2b(q.z); v[i][3] = f2b(q.w);
  }
  const int phys = (g ^ ((m & 3) << 2)) * 4;
#pragma unroll
  for (int j = 0; j < 4; ++j) {
    int c = 4 * m + j;
    bvec4 o; o[0] = (short)v[0][j]; o[1] = (short)v[1][j];
    o[2] = (short)v[2][j]; o[3] = (short)v[3][j];
    *(bvec4*)&tile[c * 72 + phys] = o;
  }
  __syncthreads();
  const int cl = t >> 2;
  const int q  = t & 3;
  const int base = ((q ^ ((cl >> 2) & 3)) << 4);
  bvec8 ra = *(const bvec8*)&tile[cl * 72 + base];
  bvec8 rb = *(const bvec8*)&tile[cl * 72 + base + 8];
  u16* dp = dst + (size_t)(c0 + cl) * FFN + r0 + 16 * q;
  *(bvec8*)(dp + 0) = ra;
  *(bvec8*)(dp + 8) = rb;
}

// gemm1 body: 128x128, BK=64, R6 2-barrier structure (proven 742 TF config).
__device__ void gemm1_body(const u16* __restrict__ xb, const u16* __restrict__ bi,
                           const int* __restrict__ rowmap, const int4* __restrict__ tilemap,
                           u16* __restrict__ hbuf, int bid, int tid,
                           u16* __restrict__ As, u16* __restrict__ Bs) {
  const int wg = xcd_swz(bid, NT1 * MAXT);
  const int mt = wg % MAXT;
  const int nt = wg / MAXT;
  int4 ti = tilemap[mt];
  if (ti.x < 0) return;
  const int e = ti.x, rowbase = ti.y, mvalid = ti.z;
  const int n0 = nt * BN;

  const int lane = tid & 63;
  const int wv = tid >> 6;
  const int srow = tid >> 3;
  const int csrc = ((tid & 7) ^ (srow & 7)) * 8;
  const u16* wb = bi + (size_t)e * FFI * HID;
  const u16* gA[4]; const u16* gB[4];
  u16* lA[4]; u16* lB[4];
#pragma unroll
  for (int r = 0; r < 4; ++r) {
    int row = r * 32 + srow;
    int tok = rowmap[min(rowbase + row, RTOT - 1)];
    gA[r] = xb + (size_t)tok * HID + csrc;
    gB[r] = wb + (size_t)(n0 + row) * HID + csrc;
    lA[r] = &As[(r * 32 + wv * 8) * BK];
    lB[r] = &Bs[(r * 32 + wv * 8) * BK];
  }

  const int wm = (tid >> 7) & 1, wn = (tid >> 6) & 1;
  const int l15 = lane & 15;
  const int kg = lane >> 4;
  const int swz = l15 & 7;
  const int aBase = (wm * 64 + l15) * BK;
  const int bBase = (wn * 64 + l15) * BK;
  const int ch0 = ((0 + kg) ^ swz) * 8;
  const int ch1 = ((4 + kg) ^ swz) * 8;

  fvec4 acc[4][4] = {};

  for (int kt = 0; kt < HID / BK; ++kt) {
#pragma unroll
    for (int r = 0; r < 4; ++r) { gload16(gA[r], lA[r]); gA[r] += BK; }
#pragma unroll
    for (int r = 0; r < 4; ++r) { gload16(gB[r], lB[r]); gB[r] += BK; }
    __syncthreads();
    bvec8 a0[4], a1[4];
#pragma unroll
    for (int mi = 0; mi < 4; ++mi) {
      a0[mi] = *(const bvec8*)&As[aBase + mi * 16 * BK + ch0];
      a1[mi] = *(const bvec8*)&As[aBase + mi * 16 * BK + ch1];
    }
#pragma unroll
    for (int ni = 0; ni < 4; ++ni) {
      bvec8 b0 = *(const bvec8*)&Bs[bBase + ni * 16 * BK + ch0];
#pragma unroll
      for (int mi = 0; mi < 4; ++mi)
        acc[mi][ni] = __builtin_amdgcn_mfma_f32_16x16x32_bf16(a0[mi], b0, acc[mi][ni], 0, 0, 0);
      bvec8 b1 = *(const bvec8*)&Bs[bBase + ni * 16 * BK + ch1];
#pragma unroll
      for (int mi = 0; mi < 4; ++mi)
        acc[mi][ni] = __builtin_amdgcn_mfma_f32_16x16x32_bf16(a1[mi], b1, acc[mi][ni], 0, 0, 0);
    }
    __syncthreads();
  }
  const int rg4 = (lane >> 4) * 4;
#pragma unroll
  for (int mi = 0; mi < 4; ++mi) {
#pragma unroll
    for (int j = 0; j < 4; ++j) {
      int ml = wm * 64 + mi * 16 + rg4 + j;
      if (ml < mvalid) {
        size_t rowoff = (size_t)(rowbase + ml) * FFN + ((n0 + wn * 64) >> 1);
#pragma unroll
        for (int np = 0; np < 2; ++np) {
          float g = acc[mi][2 * np][j], u = acc[mi][2 * np + 1][j];
          float hv = (g / (1.f + expf(-g))) * u;
          hbuf[rowoff + np * 16 + l15] = f2b(hv);
        }
      }
    }
  }
}

// ================= global kernels =======================================================

// fused: router blocks first (overlap within transpose window), then dual-transpose
__global__ void fused_pre_kernel(const float* __restrict__ x, const float* __restrict__ gw,
                                 const float* __restrict__ w1, const float* __restrict__ w3,
                                 float* __restrict__ logits, int* __restrict__ tk_id,
                                 float* __restrict__ tk_w, int* __restrict__ counts,
                                 u16* __restrict__ xb, u16* __restrict__ bi) {
  __shared__ __attribute__((aligned(16))) u16 tile[64 * 72];
  const int bid = blockIdx.x;
  if (bid < RTRBLKS) {
    router_body(x, gw, logits, tk_id, tk_w, counts, xb, bid, threadIdx.x);
  } else {
    int did = bid - RTRBLKS;
    int bx = did % (FFN / 64); int rest = did / (FFN / 64);
    int by = rest % (HID / 64); int bz = rest / (HID / 64);
    dualT_body(w1, w3, bi, bx, by, bz, threadIdx.x, tile);
  }
}

// fused: gemm1 blocks first (5.25 rounds), w2-transpose fills the ragged tail
__launch_bounds__(256, 3)
__global__ void fused_g1w2_kernel(const u16* __restrict__ xb, const u16* __restrict__ bi,
                                  const int* __restrict__ rowmap,
                                  const int4* __restrict__ tilemap, u16* __restrict__ hbuf,
                                  const float* __restrict__ w2, u16* __restrict__ w2t) {
  __shared__ __attribute__((aligned(128))) u16 As[BM * BK];   // 16KB
  __shared__ __attribute__((aligned(128))) u16 Bs[BN * BK];   // 16KB
  const int bid = blockIdx.x;
  if (bid < G1BLKS) {
    gemm1_body(xb, bi, rowmap, tilemap, hbuf, bid, threadIdx.x, As, Bs);
  } else {
    int id = bid - G1BLKS;
    int bx = id % (HID / 64); int rest = id / (HID / 64);
    int by = rest % (FFN / 64); int e = rest / (FFN / 64);
    w2T_body(w2, w2t, bx, by, e, threadIdx.x, As);
  }
}

// standalone versions (fallback serial path)
__global__ void router_kernel(const float* __restrict__ x, const float* __restrict__ gw,
                              float* __restrict__ logits, int* __restrict__ tk_id,
                              float* __restrict__ tk_w, int* __restrict__ counts,
                              u16* __restrict__ xb) {
  router_body(x, gw, logits, tk_id, tk_w, counts, xb, blockIdx.x, threadIdx.x);
}
__global__ void transpose_cast_dual_kernel(const float* __restrict__ w1,
                                           const float* __restrict__ w3,
                                           u16* __restrict__ bi) {
  __shared__ __attribute__((aligned(16))) u16 tile[64 * 72];
  dualT_body(w1, w3, bi, blockIdx.x, blockIdx.y, blockIdx.z, threadIdx.x, tile);
}
__global__ void transpose_cast_w2_kernel(const float* __restrict__ w2, u16* __restrict__ w2t) {
  __shared__ __attribute__((aligned(16))) u16 tile[64 * 72];
  w2T_body(w2, w2t, blockIdx.x, blockIdx.y, blockIdx.z, threadIdx.x, tile);
}
__launch_bounds__(256, 3)
__global__ void gemm1_kernel(const u16* __restrict__ xb, const u16* __restrict__ bi,
                             const int* __restrict__ rowmap,
                             const int4* __restrict__ tilemap, u16* __restrict__ hbuf) {
  __shared__ __attribute__((aligned(128))) u16 As[BM * BK];
  __shared__ __attribute__((aligned(128))) u16 Bs[BN * BK];
  gemm1_body(xb, bi, rowmap, tilemap, hbuf, blockIdx.x, threadIdx.x, As, Bs);
}

// ---------------- scan: offsets + tile map, parallel ------------------------------------
__global__ void scan_kernel(const int* __restrict__ counts, int* __restrict__ offsets,
                            int* __restrict__ cursors, int4* __restrict__ tilemap) {
  __shared__ int c[NEXP];
  __shared__ int tbase[NEXP + 1];
  const int t = threadIdx.x;
  if (t < NEXP) c[t] = counts[t * CPAD];
  __syncthreads();
  if (t < NEXP) {
    int off = 0, tiles = 0;
    for (int e = 0; e < t; ++e) { off += c[e]; tiles += (c[e] + BM - 1) / BM; }
    offsets[t] = off; cursors[t * CPAD] = 0;
    if (t == NEXP - 1) {
      offsets[NEXP] = off + c[t];
      tbase[NEXP] = tiles + (c[t] + BM - 1) / BM;
    }
    tbase[t] = tiles;
    const int cc = c[t];
    for (int tm = 0; tm * BM < cc; ++tm)
      tilemap[tiles + tm] = make_int4(t, off + tm * BM, min(BM, cc - tm * BM), 0);
  }
  __syncthreads();
  for (int i = tbase[NEXP] + t; i < MAXT; i += 64)
    tilemap[i] = make_int4(-1, 0, 0, 0);
}

// ---------------- scatter: wave-aggregated (1 atomic per wave per expert) ---------------
__global__ void scatter_kernel(const int* __restrict__ tk_id, const float* __restrict__ tk_w,
                               const int* __restrict__ offsets, int* __restrict__ cursors,
                               int* __restrict__ rowmap, float* __restrict__ roww,
                               int* __restrict__ tokrow) {
  int i = blockIdx.x * 256 + threadIdx.x;      // 0 .. RTOT-1
  int t = i >> 1;
  int e = tk_id[i]; float w = tk_w[i];
  const int lane = threadIdx.x & 63;
  const unsigned long long lt = (lane == 63) ? ~0ull >> 1 : (1ull << lane) - 1ull;
  int base = 0, rank = 0;
#pragma unroll
  for (int ex = 0; ex < NEXP; ++ex) {          // wave-uniform loop
    unsigned long long m = __ballot(e == ex);
    if (e == ex) {
      int cnt = __popcll(m);
      int leader = __ffsll((long long)m) - 1;
      int b = 0;
      if (lane == leader) b = atomicAdd(&cursors[ex * CPAD], cnt);
      b = __shfl(b, leader, 64);
      base = b; rank = __popcll(m & lt);
    }
  }
  int r = offsets[e] + base + rank;
  rowmap[r] = t; roww[r] = w;
  tokrow[i] = r;
}

// ---------------- GEMM2: 128x128, BK=64, split-K x2, STORE epilogue; 3 blocks/CU --------
__launch_bounds__(256, 3)
__global__ void gemm2_kernel(const u16* __restrict__ hbuf, const u16* __restrict__ w2t,
                             const float* __restrict__ roww,
                             const int4* __restrict__ tilemap, u16* __restrict__ part) {
  const int wg = xcd_swz(blockIdx.x, NT2 * MAXT * SPLITK2);
  const int mt = wg % MAXT;
  const int rest = wg / MAXT;
  const int nt = rest % NT2;
  const int sk = rest / NT2;
  int4 ti = tilemap[mt];
  if (ti.x < 0) return;
  const int e = ti.x, rowbase = ti.y, mvalid = ti.z;
  const int n0 = nt * BN;
  const int k0 = sk * KCH2;

  __shared__ __attribute__((aligned(128))) u16 As[BM * BK];
  __shared__ __attribute__((aligned(128))) u16 Bs[BN * BK];

  const int tid = threadIdx.x;
  const int lane = tid & 63;
  const int wv = tid >> 6;

  const int srow = tid >> 3;
  const int csrc = ((tid & 7) ^ (srow & 7)) * 8;
  const u16* wb2 = w2t + (size_t)e * HID * FFN;
  const u16* gA[4]; const u16* gB[4];
  u16* lA[4]; u16* lB[4];
#pragma unroll
  for (int r = 0; r < 4; ++r) {
    int row = r * 32 + srow;
    gA[r] = hbuf + (size_t)min(rowbase + row, RTOT - 1) * FFN + k0 + csrc;
    gB[r] = wb2 + (size_t)(n0 + row) * FFN + k0 + csrc;
    lA[r] = &As[(r * 32 + wv * 8) * BK];
    lB[r] = &Bs[(r * 32 + wv * 8) * BK];
  }

  const int wm = (tid >> 7) & 1, wn = (tid >> 6) & 1;
  const int l15 = lane & 15;
  const int kg = lane >> 4;
  const int swz = l15 & 7;
  const int aBase = (wm * 64 + l15) * BK;
  const int bBase = (wn * 64 + l15) * BK;
  const int ch0 = ((0 + kg) ^ swz) * 8;
  const int ch1 = ((4 + kg) ^ swz) * 8;

  fvec4 acc[4][4] = {};

  for (int kt = 0; kt < KCH2 / BK; ++kt) {
#pragma unroll
    for (int r = 0; r < 4; ++r) { gload16(gA[r], lA[r]); gA[r] += BK; }
#pragma unroll
    for (int r = 0; r < 4; ++r) { gload16(gB[r], lB[r]); gB[r] += BK; }
    __syncthreads();
    bvec8 a0[4], a1[4];
#pragma unroll
    for (int mi = 0; mi < 4; ++mi) {
      a0[mi] = *(const bvec8*)&As[aBase + mi * 16 * BK + ch0];
      a1[mi] = *(const bvec8*)&As[aBase + mi * 16 * BK + ch1];
    }
#pragma unroll
    for (int ni = 0; ni < 4; ++ni) {
      bvec8 b0 = *(const bvec8*)&Bs[bBase + ni * 16 * BK + ch0];
#pragma unroll
      for (int mi = 0; mi < 4; ++mi)
        acc[mi][ni] = __builtin_amdgcn_mfma_f32_16x16x32_bf16(a0[mi], b0, acc[mi][ni], 0, 0, 0);
      bvec8 b1 = *(const bvec8*)&Bs[bBase + ni * 16 * BK + ch1];
#pragma unroll
      for (int mi = 0; mi < 4; ++mi)
        acc[mi][ni] = __builtin_amdgcn_mfma_f32_16x16x32_bf16(a1[mi], b1, acc[mi][ni], 0, 0, 0);
    }
    __syncthreads();
  }
  u16* pp = part + (size_t)sk * RTOT * HID;
  const int rg4 = (lane >> 4) * 4;
#pragma unroll
  for (int mi = 0; mi < 4; ++mi) {
#pragma unroll
    for (int j = 0; j < 4; ++j) {
      int ml = wm * 64 + mi * 16 + rg4 + j;
      if (ml < mvalid) {
        int r = rowbase + ml;
        float wgt = roww[r];
        u16* op = pp + (size_t)r * HID + n0 + wn * 64;
#pragma unroll
        for (int ni = 0; ni < 4; ++ni)
          op[ni * 16 + l15] = f2b(acc[mi][ni][j] * wgt);
      }
    }
  }
}

// ---------------- combine: out[t] = sum over {2 slots} x {2 K-halves} of partials -------
__global__ void combine_kernel(const u16* __restrict__ part, const int* __restrict__ tokrow,
                               float* __restrict__ out) {
  int idx = blockIdx.x * 256 + threadIdx.x;
  int t = idx >> 7;
  int c = (idx & 127) * 8;
  int r0 = tokrow[2 * t], r1 = tokrow[2 * t + 1];
  const size_t sk1 = (size_t)RTOT * HID;
  bvec8 a = *(const bvec8*)(part + (size_t)r0 * HID + c);
  bvec8 b = *(const bvec8*)(part + sk1 + (size_t)r0 * HID + c);
  bvec8 d = *(const bvec8*)(part + (size_t)r1 * HID + c);
  bvec8 f = *(const bvec8*)(part + sk1 + (size_t)r1 * HID + c);
  float* dst = out + (size_t)t * HID + c;
#pragma unroll
  for (int k = 0; k < 8; ++k)
    dst[k] = (b2f((u16)a[k]) + b2f((u16)b[k])) + (b2f((u16)d[k]) + b2f((u16)f[k]));
}

// ---------------- launcher --------------------------------------------------------------
extern "C" void kernel_launch(void* const* d_in, const int* in_sizes, int n_in,
                              void* d_out, int out_size, void* d_ws, size_t ws_size,
                              hipStream_t stream) {
  (void)in_sizes; (void)n_in; (void)out_size;
  const float* x  = (const float*)d_in[0];
  const float* gw = (const float*)d_in[1];
  const float* w1 = (const float*)d_in[2];
  const float* w2 = (const float*)d_in[3];   // NOTE: dict order is w1, w2, w3
  const float* w3 = (const float*)d_in[4];
  float* out = (float*)d_out;
  float* logits = out + (size_t)T_TOK * HID;

  size_t off = 0;
  auto take = [&](size_t b) { size_t o = off; off += (b + 255) & ~(size_t)255; return o; };
  size_t o_xb   = take((size_t)T_TOK * HID * 2);           // x bf16
  size_t o_wt   = take((size_t)NEXP * FFI * HID * 2);      // Bi; part reuses back after gemm1
  size_t o_hb   = take((size_t)RTOT * FFN * 2);            // h bf16
  size_t o_rmap = take((size_t)RTOT * 4);
  size_t o_rw   = take((size_t)RTOT * 4);
  size_t o_tid  = take((size_t)RTOT * 4);
  size_t o_tw   = take((size_t)RTOT * 4);
  size_t o_trow = take((size_t)RTOT * 4);
  size_t o_cnt  = take(4 * NEXP * CPAD);
  size_t o_ofs  = take(4 * (NEXP + 1));
  size_t o_cur  = take(4 * NEXP * CPAD);
  size_t o_tmap = take(MAXT * 16);
  size_t total_base = off;
  size_t o_w2t  = take((size_t)NEXP * HID * FFN * 2);      // separate w2t (fused path only)
  size_t total_fused = off;

  if (ws_size < total_base) {
    hipMemsetAsync(d_out, 0, (size_t)T_TOK * HID * sizeof(float), stream);
    router_kernel<<<RTRBLKS, 256, 0, stream>>>(x, gw, logits, nullptr, nullptr, nullptr,
                                               nullptr);
    return;
  }
  const bool fused = (ws_size >= total_fused);

  char* w = (char*)d_ws;
  u16* xb   = (u16*)(w + o_xb);
  u16* bi   = (u16*)(w + o_wt);
  u16* part = bi + (size_t)NEXP * HID * FFN;        // back region of Bi, free after gemm1
  u16* hb   = (u16*)(w + o_hb);
  int*   rmap = (int*)(w + o_rmap);
  float* rw   = (float*)(w + o_rw);
  int*   tkid = (int*)(w + o_tid);
  float* tkw  = (float*)(w + o_tw);
  int*   trow = (int*)(w + o_trow);
  int*   cnt  = (int*)(w + o_cnt);
  int*   ofs  = (int*)(w + o_ofs);
  int*   cur  = (int*)(w + o_cur);
  int4*  tmap = (int4*)(w + o_tmap);
  u16* w2t = fused ? (u16*)(w + o_w2t) : bi;        // fallback reuses Bi front after gemm1

  hipMemsetAsync(cnt, 0, 4 * NEXP * CPAD, stream);
  if (fused) {
    fused_pre_kernel<<<RTRBLKS + DTBLKS, 256, 0, stream>>>(x, gw, w1, w3, logits, tkid, tkw,
                                                           cnt, xb, bi);
    scan_kernel<<<1, 64, 0, stream>>>(cnt, ofs, cur, tmap);
    scatter_kernel<<<RTOT / 256, 256, 0, stream>>>(tkid, tkw, ofs, cur, rmap, rw, trow);
    fused_g1w2_kernel<<<G1BLKS + W2TBLKS, 256, 0, stream>>>(xb, bi, rmap, tmap, hb, w2, w2t);
  } else {
    router_kernel<<<RTRBLKS, 256, 0, stream>>>(x, gw, logits, tkid, tkw, cnt, xb);
    scan_kernel<<<1, 64, 0, stream>>>(cnt, ofs, cur, tmap);
    scatter_kernel<<<RTOT / 256, 256, 0, stream>>>(tkid, tkw, ofs, cur, rmap, rw, trow);
    transpose_cast_dual_kernel<<<dim3(FFN / 64, HID / 64, 2 * NEXP), 256, 0, stream>>>(w1, w3, bi);
    gemm1_kernel<<<G1BLKS, 256, 0, stream>>>(xb, bi, rmap, tmap, hb);
    transpose_cast_w2_kernel<<<dim3(HID / 64, FFN / 64, NEXP), 256, 0, stream>>>(w2, w2t);
  }
  gemm2_kernel<<<NT2 * MAXT * SPLITK2, 256, 0, stream>>>(hb, w2t, rw, tmap, part);
  combine_kernel<<<T_TOK * HID / 8 / 256, 256, 0, stream>>>(part, trow, out);
}